// Round 1
// baseline (245.131 us; speedup 1.0000x reference)
//
#include <hip/hip_runtime.h>
#include <hip/hip_bf16.h>
#include <cmath>

// Problem constants (from reference)
#define BATCH   2
#define NQ      5376
#define NV      5376
#define CDIM    256
#define HEADS   8
#define HD      32
#define LEVELS  3
#define POINTS  4
#define TP      96      // HEADS*LEVELS*POINTS
#define MROWS   (BATCH*NQ)   // 10752

// ---------------------------------------------------------------------------
// Generic fp32 SGEMM: C[m,n] = sum_k A[m,k] * W[n,k] + bias[n]
// A: (M,K) row-major, W: (N,K) row-major (i.e. computes A @ W^T + bias)
// Tile 64x64x16, 256 threads, 4x4 micro-tile per thread.
// Requires K % 16 == 0 and 16B-aligned rows (K % 4 == 0). M,N guarded.
// ---------------------------------------------------------------------------
#define BM 64
#define BN 64
#define BK 16
#define LDS_PAD 4   // pad to 68 floats/row: keeps float4 LDS reads 16B-aligned

__global__ __launch_bounds__(256) void sgemm_bias_kernel(
    const float* __restrict__ A, const float* __restrict__ W,
    const float* __restrict__ bias, float* __restrict__ C,
    int M, int N, int K)
{
    __shared__ float As[BK][BM + LDS_PAD];
    __shared__ float Ws[BK][BN + LDS_PAD];

    const int m0 = blockIdx.x * BM;
    const int n0 = blockIdx.y * BN;
    const int tid = threadIdx.x;
    const int tx = tid & 15;     // n direction (4 cols each)
    const int ty = tid >> 4;     // m direction (4 rows each)

    // staging indices: each thread loads one float4 of A-tile and one of W-tile
    const int lr = tid >> 2;          // 0..63 : row within tile
    const int lc = (tid & 3) * 4;     // 0,4,8,12 : k-offset within tile

    float acc[4][4] = {};

    for (int k0 = 0; k0 < K; k0 += BK) {
        float4 av = make_float4(0.f, 0.f, 0.f, 0.f);
        const int am = m0 + lr;
        if (am < M)
            av = *reinterpret_cast<const float4*>(&A[(size_t)am * K + k0 + lc]);
        As[lc + 0][lr] = av.x; As[lc + 1][lr] = av.y;
        As[lc + 2][lr] = av.z; As[lc + 3][lr] = av.w;

        float4 wv = make_float4(0.f, 0.f, 0.f, 0.f);
        const int wn = n0 + lr;
        if (wn < N)
            wv = *reinterpret_cast<const float4*>(&W[(size_t)wn * K + k0 + lc]);
        Ws[lc + 0][lr] = wv.x; Ws[lc + 1][lr] = wv.y;
        Ws[lc + 2][lr] = wv.z; Ws[lc + 3][lr] = wv.w;

        __syncthreads();

        #pragma unroll
        for (int k = 0; k < BK; ++k) {
            float4 a4 = *reinterpret_cast<const float4*>(&As[k][ty * 4]);
            float4 w4 = *reinterpret_cast<const float4*>(&Ws[k][tx * 4]);
            const float am_[4] = {a4.x, a4.y, a4.z, a4.w};
            const float wn_[4] = {w4.x, w4.y, w4.z, w4.w};
            #pragma unroll
            for (int i = 0; i < 4; ++i)
                #pragma unroll
                for (int j = 0; j < 4; ++j)
                    acc[i][j] += am_[i] * wn_[j];
        }
        __syncthreads();
    }

    #pragma unroll
    for (int i = 0; i < 4; ++i) {
        const int m = m0 + ty * 4 + i;
        if (m >= M) continue;
        #pragma unroll
        for (int j = 0; j < 4; ++j) {
            const int n = n0 + tx * 4 + j;
            if (n < N)
                C[(size_t)m * N + n] = acc[i][j] + bias[n];
        }
    }
}

// ---------------------------------------------------------------------------
// MSDA core: per (b,q) block. Phase 1: clip locations + softmax over 12
// (level,point) logits per head. Phase 2: 8 heads x 32 channels bilinear
// sampling from projected values v (B,NV,256), accumulate -> t (B,NQ,256).
// ---------------------------------------------------------------------------
__global__ __launch_bounds__(256) void msda_core_kernel(
    const float* __restrict__ off,   // (B*NQ, 192)
    const float* __restrict__ alog,  // (B*NQ, 96)
    const float* __restrict__ refp,  // (B*NQ, 2)
    const float* __restrict__ v,     // (B, NV, 256)
    float* __restrict__ t)           // (B*NQ, 256)
{
    const int bq = blockIdx.x;        // 0 .. B*NQ-1
    const int b  = bq / NQ;
    const int tid = threadIdx.x;

    __shared__ float s_lx[TP], s_ly[TP], s_w[TP];

    if (tid < TP) {
        const float refx = refp[(size_t)bq * 2 + 0];
        const float refy = refp[(size_t)bq * 2 + 1];
        const float ox = off[(size_t)bq * (TP * 2) + tid * 2 + 0];
        const float oy = off[(size_t)bq * (TP * 2) + tid * 2 + 1];
        s_lx[tid] = fminf(fmaxf(refx + ox, 0.f), 1.f);
        s_ly[tid] = fminf(fmaxf(refy + oy, 0.f), 1.f);
        s_w[tid]  = alog[(size_t)bq * TP + tid];
    }
    __syncthreads();

    if (tid < HEADS) {
        float mx = -1e30f;
        #pragma unroll
        for (int i = 0; i < 12; ++i) mx = fmaxf(mx, s_w[tid * 12 + i]);
        float e[12];
        float sum = 0.f;
        #pragma unroll
        for (int i = 0; i < 12; ++i) {
            e[i] = expf(s_w[tid * 12 + i] - mx);
            sum += e[i];
        }
        const float inv = 1.f / sum;
        #pragma unroll
        for (int i = 0; i < 12; ++i) s_w[tid * 12 + i] = e[i] * inv;
    }
    __syncthreads();

    const int h  = tid >> 5;   // 0..7
    const int hd = tid & 31;   // 0..31
    // channel base pointer for this (b, h, hd); row n is at vb[n*CDIM]
    const float* vb = v + (size_t)b * NV * CDIM + h * HD + hd;

    float acc = 0.f;
    int start = 0;
    const int HWs[3][2] = {{64, 64}, {32, 32}, {16, 16}};

    #pragma unroll
    for (int l = 0; l < LEVELS; ++l) {
        const int Hh = HWs[l][0], Ww = HWs[l][1];
        #pragma unroll
        for (int p = 0; p < POINTS; ++p) {
            const int j = h * 12 + l * POINTS + p;
            const float lx = s_lx[j] * (float)Ww - 0.5f;
            const float ly = s_ly[j] * (float)Hh - 0.5f;
            const float fx0 = floorf(lx), fy0 = floorf(ly);
            const int x0 = (int)fx0, y0 = (int)fy0;
            const float wx1 = lx - fx0, wy1 = ly - fy0;
            const float wx0 = 1.f - wx1, wy0 = 1.f - wy1;

            float s = 0.f;
            {   // (x0, y0)
                const bool ok = (x0 >= 0) & (x0 < Ww) & (y0 >= 0) & (y0 < Hh);
                const float g = ok ? vb[(size_t)(start + y0 * Ww + x0) * CDIM] : 0.f;
                s += (wx0 * wy0) * g;
            }
            {   // (x0+1, y0)
                const bool ok = (x0 + 1 >= 0) & (x0 + 1 < Ww) & (y0 >= 0) & (y0 < Hh);
                const float g = ok ? vb[(size_t)(start + y0 * Ww + x0 + 1) * CDIM] : 0.f;
                s += (wx1 * wy0) * g;
            }
            {   // (x0, y0+1)
                const bool ok = (x0 >= 0) & (x0 < Ww) & (y0 + 1 >= 0) & (y0 + 1 < Hh);
                const float g = ok ? vb[(size_t)(start + (y0 + 1) * Ww + x0) * CDIM] : 0.f;
                s += (wx0 * wy1) * g;
            }
            {   // (x0+1, y0+1)
                const bool ok = (x0 + 1 >= 0) & (x0 + 1 < Ww) & (y0 + 1 >= 0) & (y0 + 1 < Hh);
                const float g = ok ? vb[(size_t)(start + (y0 + 1) * Ww + x0 + 1) * CDIM] : 0.f;
                s += (wx1 * wy1) * g;
            }
            acc += s_w[j] * s;
        }
        start += Hh * Ww;
    }

    t[(size_t)bq * CDIM + tid] = acc;
}

// ---------------------------------------------------------------------------
// Launch
// ---------------------------------------------------------------------------
extern "C" void kernel_launch(void* const* d_in, const int* in_sizes, int n_in,
                              void* d_out, int out_size, void* d_ws, size_t ws_size,
                              hipStream_t stream)
{
    const float* query = (const float*)d_in[0];   // (B,NQ,C)
    const float* refp  = (const float*)d_in[1];   // (B,NQ,2)
    const float* value = (const float*)d_in[2];   // (B,NV,C)
    const float* Wv    = (const float*)d_in[3];   // (C,C)
    const float* bv    = (const float*)d_in[4];
    const float* Woff  = (const float*)d_in[5];   // (192,C)
    const float* boff  = (const float*)d_in[6];
    const float* Wa    = (const float*)d_in[7];   // (96,C)
    const float* ba    = (const float*)d_in[8];
    const float* Wo    = (const float*)d_in[9];   // (C,C)
    const float* bo    = (const float*)d_in[10];
    float* out = (float*)d_out;

    // workspace layout (fp32): v | off | a | t   -> 34.4 MB total
    float* ws_v   = (float*)d_ws;                       // MROWS*256
    float* ws_off = ws_v   + (size_t)MROWS * CDIM;      // MROWS*192
    float* ws_a   = ws_off + (size_t)MROWS * (TP * 2);  // MROWS*96
    float* ws_t   = ws_a   + (size_t)MROWS * TP;        // MROWS*256

    const dim3 blk(256);

    // v = value @ Wv^T + bv
    sgemm_bias_kernel<<<dim3(MROWS / BM, (CDIM + BN - 1) / BN), blk, 0, stream>>>(
        value, Wv, bv, ws_v, MROWS, CDIM, CDIM);
    // off = query @ Woff^T + boff
    sgemm_bias_kernel<<<dim3(MROWS / BM, (TP * 2 + BN - 1) / BN), blk, 0, stream>>>(
        query, Woff, boff, ws_off, MROWS, TP * 2, CDIM);
    // a = query @ Wa^T + ba
    sgemm_bias_kernel<<<dim3(MROWS / BM, (TP + BN - 1) / BN), blk, 0, stream>>>(
        query, Wa, ba, ws_a, MROWS, TP, CDIM);
    // sampling core -> t
    msda_core_kernel<<<dim3(MROWS), blk, 0, stream>>>(ws_off, ws_a, refp, ws_v, ws_t);
    // out = t @ Wo^T + bo
    sgemm_bias_kernel<<<dim3(MROWS / BM, (CDIM + BN - 1) / BN), blk, 0, stream>>>(
        ws_t, Wo, bo, out, MROWS, CDIM, CDIM);
}

// Round 2
// 221.643 us; speedup vs baseline: 1.1060x; 1.1060x over previous
//
#include <hip/hip_runtime.h>
#include <hip/hip_bf16.h>
#include <cmath>

// Problem constants (from reference)
#define BATCH   2
#define NQ      5376
#define NV      5376
#define CDIM    256
#define HEADS   8
#define HD      32
#define LEVELS  3
#define POINTS  4
#define TP      96      // HEADS*LEVELS*POINTS
#define MROWS   (BATCH*NQ)   // 10752

typedef __attribute__((ext_vector_type(8))) short bf16x8;
typedef __attribute__((ext_vector_type(4))) float f32x4;

// ---------------------------------------------------------------------------
// Split-bf16 MFMA GEMM: C[m,n] = sum_k A[m,k]*W[n,k] + bias[n]  (A @ W^T + b)
// fp32 in/out. Internally A,W are split to bf16 hi+lo on the fly; product
// computed as Ah*Wh + Ah*Wl + Al*Wh (fp32 MFMA accumulate) -> ~2^-16 rel err.
// Tile: BM=128, BN=64, BK=32. 256 threads = 4 waves (2x2 of 64x32).
// Requires M % 128 == 0, K % 32 == 0. N guarded.
// ---------------------------------------------------------------------------
#define GBM 128
#define GBN 64
#define GBK 32
#define ASTR (GBK + 8)   // LDS row stride 40 shorts = 80 B: 16B-aligned, conflict-free

__device__ __forceinline__ short bf_hi(float f, float* back) {
    union { __hip_bfloat16 h; short s; } u;
    u.h = __float2bfloat16(f);
    *back = __bfloat162float(u.h);
    return u.s;
}
__device__ __forceinline__ short bf_of(float f) {
    union { __hip_bfloat16 h; short s; } u;
    u.h = __float2bfloat16(f);
    return u.s;
}

__global__ __launch_bounds__(256) void gemm_bf16x3_kernel(
    const float* __restrict__ A, const float* __restrict__ W,
    const float* __restrict__ bias, float* __restrict__ C,
    int M, int N, int K)
{
    __shared__ short Ah[GBM][ASTR];
    __shared__ short Al[GBM][ASTR];
    __shared__ short Bh[GBN][ASTR];
    __shared__ short Bl[GBN][ASTR];

    const int m0 = blockIdx.x * GBM;
    const int n0 = blockIdx.y * GBN;
    const int tid  = threadIdx.x;
    const int lane = tid & 63;
    const int wave = tid >> 6;
    const int wr   = wave & 1;    // m offset 64*wr
    const int wc   = wave >> 1;   // n offset 32*wc
    const int qm   = lane & 15;
    const int quad = lane >> 4;

    // staging map: 32 rows/pass, 8 lanes/row, float4 per lane (fully coalesced)
    const int sr = tid >> 3;        // 0..31
    const int sc = (tid & 7) * 4;   // 0,4,..,28

    f32x4 acc[4][2];
    #pragma unroll
    for (int i = 0; i < 4; ++i)
        #pragma unroll
        for (int j = 0; j < 2; ++j)
            acc[i][j] = (f32x4){0.f, 0.f, 0.f, 0.f};

    for (int k0 = 0; k0 < K; k0 += GBK) {
        // ---- stage A (128x32), 4 passes, no M guard (M % 128 == 0) ----
        #pragma unroll
        for (int p = 0; p < 4; ++p) {
            const int r = p * 32 + sr;
            const float4 v4 = *reinterpret_cast<const float4*>(
                &A[(size_t)(m0 + r) * K + k0 + sc]);
            const float vv[4] = {v4.x, v4.y, v4.z, v4.w};
            #pragma unroll
            for (int j = 0; j < 4; ++j) {
                float bk;
                const short hi = bf_hi(vv[j], &bk);
                Ah[r][sc + j] = hi;
                Al[r][sc + j] = bf_of(vv[j] - bk);
            }
        }
        // ---- stage B (64x32), 2 passes, N guarded ----
        #pragma unroll
        for (int p = 0; p < 2; ++p) {
            const int r  = p * 32 + sr;
            const int wn = n0 + r;
            float4 v4 = make_float4(0.f, 0.f, 0.f, 0.f);
            if (wn < N)
                v4 = *reinterpret_cast<const float4*>(
                    &W[(size_t)wn * K + k0 + sc]);
            const float vv[4] = {v4.x, v4.y, v4.z, v4.w};
            #pragma unroll
            for (int j = 0; j < 4; ++j) {
                float bk;
                const short hi = bf_hi(vv[j], &bk);
                Bh[r][sc + j] = hi;
                Bl[r][sc + j] = bf_of(vv[j] - bk);
            }
        }
        __syncthreads();

        // ---- fragments + MFMA ----
        bf16x8 fbh[2], fbl[2];
        #pragma unroll
        for (int ni = 0; ni < 2; ++ni) {
            const int rn = wc * 32 + ni * 16 + qm;
            fbh[ni] = *reinterpret_cast<const bf16x8*>(&Bh[rn][quad * 8]);
            fbl[ni] = *reinterpret_cast<const bf16x8*>(&Bl[rn][quad * 8]);
        }
        #pragma unroll
        for (int mi = 0; mi < 4; ++mi) {
            const int rm = wr * 64 + mi * 16 + qm;
            const bf16x8 fah = *reinterpret_cast<const bf16x8*>(&Ah[rm][quad * 8]);
            const bf16x8 fal = *reinterpret_cast<const bf16x8*>(&Al[rm][quad * 8]);
            #pragma unroll
            for (int ni = 0; ni < 2; ++ni) {
                acc[mi][ni] = __builtin_amdgcn_mfma_f32_16x16x32_bf16(
                    fah, fbh[ni], acc[mi][ni], 0, 0, 0);
                acc[mi][ni] = __builtin_amdgcn_mfma_f32_16x16x32_bf16(
                    fah, fbl[ni], acc[mi][ni], 0, 0, 0);
                acc[mi][ni] = __builtin_amdgcn_mfma_f32_16x16x32_bf16(
                    fal, fbh[ni], acc[mi][ni], 0, 0, 0);
            }
        }
        __syncthreads();
    }

    // epilogue: C/D layout col = lane&15 (n), row = quad*4 + reg (m)
    #pragma unroll
    for (int mi = 0; mi < 4; ++mi) {
        #pragma unroll
        for (int ni = 0; ni < 2; ++ni) {
            const int n = n0 + wc * 32 + ni * 16 + qm;
            if (n >= N) continue;
            const float bn = bias[n];
            #pragma unroll
            for (int r = 0; r < 4; ++r) {
                const int m = m0 + wr * 64 + mi * 16 + quad * 4 + r;
                C[(size_t)m * N + n] = acc[mi][ni][r] + bn;
            }
        }
    }
}

// ---------------------------------------------------------------------------
// MSDA core, v2: phase A (96 threads) computes per-point tap byte-offsets
// (clamped) and tap weights (premultiplied by softmax attention, zeroed when
// out of bounds) into LDS. Phase B: 8 heads x 32 channels, per point 2
// broadcast LDS b128 reads + 4 unconditional load+fma.
// ---------------------------------------------------------------------------
__global__ __launch_bounds__(256) void msda_core_kernel(
    const float* __restrict__ off,   // (B*NQ, 192)
    const float* __restrict__ alog,  // (B*NQ, 96)
    const float* __restrict__ refp,  // (B*NQ, 2)
    const float* __restrict__ v,     // (B, NV, 256)
    float* __restrict__ t)           // (B*NQ, 256)
{
    const int bq  = blockIdx.x;
    const int b   = bq / NQ;
    const int tid = threadIdx.x;

    __shared__ float s_w[TP];
    __shared__ int   s_idx[TP][4];   // byte offsets (row * CDIM * 4)
    __shared__ float s_twt[TP][4];   // attention * bilinear weight (0 if invalid)

    if (tid < TP) s_w[tid] = alog[(size_t)bq * TP + tid];
    __syncthreads();

    if (tid < HEADS) {
        float mx = -1e30f;
        #pragma unroll
        for (int i = 0; i < 12; ++i) mx = fmaxf(mx, s_w[tid * 12 + i]);
        float e[12];
        float sum = 0.f;
        #pragma unroll
        for (int i = 0; i < 12; ++i) {
            e[i] = expf(s_w[tid * 12 + i] - mx);
            sum += e[i];
        }
        const float inv = 1.f / sum;
        #pragma unroll
        for (int i = 0; i < 12; ++i) s_w[tid * 12 + i] = e[i] * inv;
    }
    __syncthreads();

    if (tid < TP) {
        const int j  = tid;
        const int jj = j % 12;        // within-head point index
        const int l  = jj >> 2;       // level
        const int Wl    = (l == 0) ? 64 : (l == 1) ? 32 : 16;
        const int Hl    = Wl;
        const int start = (l == 0) ? 0 : (l == 1) ? 4096 : 5120;

        const float refx = refp[(size_t)bq * 2 + 0];
        const float refy = refp[(size_t)bq * 2 + 1];
        const float lx = fminf(fmaxf(refx + off[(size_t)bq * (TP * 2) + j * 2 + 0], 0.f), 1.f) * (float)Wl - 0.5f;
        const float ly = fminf(fmaxf(refy + off[(size_t)bq * (TP * 2) + j * 2 + 1], 0.f), 1.f) * (float)Hl - 0.5f;
        const float fx0 = floorf(lx), fy0 = floorf(ly);
        const int   x0  = (int)fx0,   y0  = (int)fy0;
        const float wx1 = lx - fx0,   wy1 = ly - fy0;
        const float wx0 = 1.f - wx1,  wy0 = 1.f - wy1;
        const float aw  = s_w[j];

        #pragma unroll
        for (int k = 0; k < 4; ++k) {
            const int dx = k & 1, dy = k >> 1;
            const int xi = x0 + dx, yi = y0 + dy;
            const bool ok = (xi >= 0) & (xi < Wl) & (yi >= 0) & (yi < Hl);
            const int xc = min(max(xi, 0), Wl - 1);
            const int yc = min(max(yi, 0), Hl - 1);
            s_idx[j][k] = (start + yc * Wl + xc) * (CDIM * 4);
            const float wxy = (dx ? wx1 : wx0) * (dy ? wy1 : wy0);
            s_twt[j][k] = ok ? aw * wxy : 0.f;
        }
    }
    __syncthreads();

    const int h  = tid >> 5;
    const int hd = tid & 31;
    const char* vb = (const char*)(v + (size_t)b * NV * CDIM + h * HD + hd);

    float acc = 0.f;
    #pragma unroll
    for (int jj = 0; jj < 12; ++jj) {
        const int j = h * 12 + jj;
        const int4   ix = *reinterpret_cast<const int4*>(&s_idx[j][0]);
        const float4 tw = *reinterpret_cast<const float4*>(&s_twt[j][0]);
        acc += tw.x * *reinterpret_cast<const float*>(vb + ix.x);
        acc += tw.y * *reinterpret_cast<const float*>(vb + ix.y);
        acc += tw.z * *reinterpret_cast<const float*>(vb + ix.z);
        acc += tw.w * *reinterpret_cast<const float*>(vb + ix.w);
    }

    t[(size_t)bq * CDIM + tid] = acc;
}

// ---------------------------------------------------------------------------
// Launch
// ---------------------------------------------------------------------------
extern "C" void kernel_launch(void* const* d_in, const int* in_sizes, int n_in,
                              void* d_out, int out_size, void* d_ws, size_t ws_size,
                              hipStream_t stream)
{
    const float* query = (const float*)d_in[0];   // (B,NQ,C)
    const float* refp  = (const float*)d_in[1];   // (B,NQ,2)
    const float* value = (const float*)d_in[2];   // (B,NV,C)
    const float* Wv    = (const float*)d_in[3];   // (C,C)
    const float* bv    = (const float*)d_in[4];
    const float* Woff  = (const float*)d_in[5];   // (192,C)
    const float* boff  = (const float*)d_in[6];
    const float* Wa    = (const float*)d_in[7];   // (96,C)
    const float* ba    = (const float*)d_in[8];
    const float* Wo    = (const float*)d_in[9];   // (C,C)
    const float* bo    = (const float*)d_in[10];
    float* out = (float*)d_out;

    // workspace layout (fp32): v | off | a | t   -> 34.4 MB total
    float* ws_v   = (float*)d_ws;                       // MROWS*256
    float* ws_off = ws_v   + (size_t)MROWS * CDIM;      // MROWS*192
    float* ws_a   = ws_off + (size_t)MROWS * (TP * 2);  // MROWS*96
    float* ws_t   = ws_a   + (size_t)MROWS * TP;        // MROWS*256

    const dim3 blk(256);

    // v = value @ Wv^T + bv
    gemm_bf16x3_kernel<<<dim3(MROWS / GBM, CDIM / GBN), blk, 0, stream>>>(
        value, Wv, bv, ws_v, MROWS, CDIM, CDIM);
    // off = query @ Woff^T + boff  (N=192 -> 3 full col-tiles)
    gemm_bf16x3_kernel<<<dim3(MROWS / GBM, (TP * 2 + GBN - 1) / GBN), blk, 0, stream>>>(
        query, Woff, boff, ws_off, MROWS, TP * 2, CDIM);
    // a = query @ Wa^T + ba  (N=96 -> 2 col-tiles, guarded)
    gemm_bf16x3_kernel<<<dim3(MROWS / GBM, (TP + GBN - 1) / GBN), blk, 0, stream>>>(
        query, Wa, ba, ws_a, MROWS, TP, CDIM);
    // sampling core -> t
    msda_core_kernel<<<dim3(MROWS), blk, 0, stream>>>(ws_off, ws_a, refp, ws_v, ws_t);
    // out = t @ Wo^T + bo
    gemm_bf16x3_kernel<<<dim3(MROWS / GBM, CDIM / GBN), blk, 0, stream>>>(
        ws_t, Wo, bo, out, MROWS, CDIM, CDIM);
}

// Round 3
// 173.504 us; speedup vs baseline: 1.4128x; 1.2774x over previous
//
#include <hip/hip_runtime.h>
#include <hip/hip_bf16.h>
#include <cmath>

// Problem constants (from reference)
#define BATCH   2
#define NQ      5376
#define NV      5376
#define CDIM    256
#define HEADS   8
#define HD      32
#define LEVELS  3
#define POINTS  4
#define TP      96      // HEADS*LEVELS*POINTS
#define MROWS   (BATCH*NQ)   // 10752

typedef __attribute__((ext_vector_type(8))) short bf16x8;
typedef __attribute__((ext_vector_type(4))) float f32x4;
typedef unsigned short u16;
typedef unsigned int   u32;

#define AS1 __attribute__((address_space(1)))
#define AS3 __attribute__((address_space(3)))

__device__ __forceinline__ void g2lds16(const void* g, void* l) {
    // async global->LDS, 16B per lane; LDS dest = wave-uniform base + lane*16
    __builtin_amdgcn_global_load_lds((const AS1 void*)g, (AS3 void*)l, 16, 0, 0);
}

__device__ __forceinline__ u16 bf_of(float f) {
    union { __hip_bfloat16 h; u16 s; } u;
    u.h = __float2bfloat16(f);
    return u.s;
}
__device__ __forceinline__ float bf_back(u16 s) {
    return __uint_as_float((u32)s << 16);
}

// ---------------------------------------------------------------------------
// split: fp32 x -> bf16 hi (RNE) + bf16 lo (RNE of residual). float4-vectorized.
// ---------------------------------------------------------------------------
__global__ __launch_bounds__(256) void split_kernel(
    const float* __restrict__ x, u16* __restrict__ hi, u16* __restrict__ lo, int n4)
{
    const int i = blockIdx.x * 256 + threadIdx.x;
    if (i >= n4) return;
    const float4 v = reinterpret_cast<const float4*>(x)[i];
    ushort4 h, l;
    h.x = bf_of(v.x); l.x = bf_of(v.x - bf_back(h.x));
    h.y = bf_of(v.y); l.y = bf_of(v.y - bf_back(h.y));
    h.z = bf_of(v.z); l.z = bf_of(v.z - bf_back(h.z));
    h.w = bf_of(v.w); l.w = bf_of(v.w - bf_back(h.w));
    reinterpret_cast<ushort4*>(hi)[i] = h;
    reinterpret_cast<ushort4*>(lo)[i] = l;
}

// ---------------------------------------------------------------------------
// Split-bf16 MFMA GEMM, m97-style staging: C = A @ W^T + bias, fp32-accurate
// via Ah*Bh + Ah*Bl + Al*Bh. A,W pre-split to bf16 hi/lo in global memory.
// Tile 128x64x32, 256 threads (4 waves, 2x2 of 64x32). global_load_lds x16
// staging, unpadded row-major LDS [rows][32] bf16.
// Requires M % 128 == 0, K % 32 == 0. N guarded (B rows clamped, stores guarded).
// OUTMODE: 0 = fp32 out, 1 = bf16 out.
// ---------------------------------------------------------------------------
#define GBM 128
#define GBN 64
#define GBK 32

template <int OUTMODE>
__global__ __launch_bounds__(256) void gemm_split_kernel(
    const u16* __restrict__ Ah, const u16* __restrict__ Al,
    const u16* __restrict__ Bh, const u16* __restrict__ Bl,
    const float* __restrict__ bias, void* __restrict__ Cout,
    int M, int N, int K)
{
    __shared__ u16 sAh[GBM * GBK];   // 8 KB
    __shared__ u16 sAl[GBM * GBK];   // 8 KB
    __shared__ u16 sBh[GBN * GBK];   // 4 KB
    __shared__ u16 sBl[GBN * GBK];   // 4 KB

    const int m0 = blockIdx.x * GBM;
    const int n0 = blockIdx.y * GBN;
    const int tid  = threadIdx.x;
    const int lane = tid & 63;
    const int wave = tid >> 6;
    const int wr   = wave & 1;     // m offset 64*wr
    const int wc   = wave >> 1;    // n offset 32*wc
    const int qm   = lane & 15;
    const int quad = lane >> 4;

    f32x4 acc[4][2];
    #pragma unroll
    for (int i = 0; i < 4; ++i)
        #pragma unroll
        for (int j = 0; j < 2; ++j)
            acc[i][j] = (f32x4){0.f, 0.f, 0.f, 0.f};

    // staging geometry: chunk c -> row = c>>2, k-offset = (c&3)*8 bf16
    // A tile: 8 instrs (2/wave), B tile: 4 instrs (1/wave)
    const int cA0 = (wave * 2 + 0) * 64 + lane;
    const int cA1 = (wave * 2 + 1) * 64 + lane;
    const int cB  = wave * 64 + lane;
    const int arow0 = cA0 >> 2, ak0 = (cA0 & 3) * 8;
    const int arow1 = cA1 >> 2, ak1 = (cA1 & 3) * 8;
    const int brow  = cB >> 2,  bk  = (cB & 3) * 8;
    const int brc   = min(n0 + brow, N - 1);   // clamp OOB rows (results discarded)

    for (int k0 = 0; k0 < K; k0 += GBK) {
        const size_t ga0 = (size_t)(m0 + arow0) * K + k0 + ak0;
        const size_t ga1 = (size_t)(m0 + arow1) * K + k0 + ak1;
        const size_t gb  = (size_t)brc * K + k0 + bk;
        g2lds16(Ah + ga0, sAh + (wave * 2 + 0) * 512);
        g2lds16(Ah + ga1, sAh + (wave * 2 + 1) * 512);
        g2lds16(Al + ga0, sAl + (wave * 2 + 0) * 512);
        g2lds16(Al + ga1, sAl + (wave * 2 + 1) * 512);
        g2lds16(Bh + gb,  sBh + wave * 512);
        g2lds16(Bl + gb,  sBl + wave * 512);
        __syncthreads();

        bf16x8 fbh[2], fbl[2];
        #pragma unroll
        for (int ni = 0; ni < 2; ++ni) {
            const int rn = wc * 32 + ni * 16 + qm;
            fbh[ni] = *reinterpret_cast<const bf16x8*>(&sBh[rn * GBK + quad * 8]);
            fbl[ni] = *reinterpret_cast<const bf16x8*>(&sBl[rn * GBK + quad * 8]);
        }
        #pragma unroll
        for (int mi = 0; mi < 4; ++mi) {
            const int rm = wr * 64 + mi * 16 + qm;
            const bf16x8 fah = *reinterpret_cast<const bf16x8*>(&sAh[rm * GBK + quad * 8]);
            const bf16x8 fal = *reinterpret_cast<const bf16x8*>(&sAl[rm * GBK + quad * 8]);
            #pragma unroll
            for (int ni = 0; ni < 2; ++ni) {
                acc[mi][ni] = __builtin_amdgcn_mfma_f32_16x16x32_bf16(
                    fah, fbh[ni], acc[mi][ni], 0, 0, 0);
                acc[mi][ni] = __builtin_amdgcn_mfma_f32_16x16x32_bf16(
                    fah, fbl[ni], acc[mi][ni], 0, 0, 0);
                acc[mi][ni] = __builtin_amdgcn_mfma_f32_16x16x32_bf16(
                    fal, fbh[ni], acc[mi][ni], 0, 0, 0);
            }
        }
        __syncthreads();
    }

    // epilogue: C/D layout col = lane&15 (n), row = quad*4 + reg (m)
    #pragma unroll
    for (int mi = 0; mi < 4; ++mi) {
        #pragma unroll
        for (int ni = 0; ni < 2; ++ni) {
            const int n = n0 + wc * 32 + ni * 16 + qm;
            if (n >= N) continue;
            const float bn = bias[n];
            #pragma unroll
            for (int r = 0; r < 4; ++r) {
                const int m = m0 + wr * 64 + mi * 16 + quad * 4 + r;
                const float val = acc[mi][ni][r] + bn;
                if (OUTMODE == 0)
                    reinterpret_cast<float*>(Cout)[(size_t)m * N + n] = val;
                else
                    reinterpret_cast<u16*>(Cout)[(size_t)m * N + n] = bf_of(val);
            }
        }
    }
}

// ---------------------------------------------------------------------------
// MSDA core v3: softmax + tap precompute (96 threads, LDS) then gather from
// bf16 v. Loads batched in groups of 8 taps to keep ~8 loads in flight.
// Output t written as bf16 hi/lo for the final GEMM.
// ---------------------------------------------------------------------------
__global__ __launch_bounds__(256) void msda_core_kernel(
    const float* __restrict__ off,   // (B*NQ, 192)
    const float* __restrict__ alog,  // (B*NQ, 96)
    const float* __restrict__ refp,  // (B*NQ, 2)
    const u16*   __restrict__ v,     // (B, NV, 256) bf16
    u16* __restrict__ t_hi,          // (B*NQ, 256) bf16
    u16* __restrict__ t_lo)          // (B*NQ, 256) bf16
{
    const int bq  = blockIdx.x;
    const int b   = bq / NQ;
    const int tid = threadIdx.x;

    __shared__ float s_w[TP];
    __shared__ int   s_idx[TP][4];   // byte offsets into bf16 v rows
    __shared__ float s_twt[TP][4];   // attention * bilinear weight (0 if invalid)

    if (tid < TP) s_w[tid] = alog[(size_t)bq * TP + tid];
    __syncthreads();

    if (tid < HEADS) {
        float mx = -1e30f;
        #pragma unroll
        for (int i = 0; i < 12; ++i) mx = fmaxf(mx, s_w[tid * 12 + i]);
        float e[12];
        float sum = 0.f;
        #pragma unroll
        for (int i = 0; i < 12; ++i) {
            e[i] = expf(s_w[tid * 12 + i] - mx);
            sum += e[i];
        }
        const float inv = 1.f / sum;
        #pragma unroll
        for (int i = 0; i < 12; ++i) s_w[tid * 12 + i] = e[i] * inv;
    }
    __syncthreads();

    if (tid < TP) {
        const int j  = tid;
        const int jj = j % 12;
        const int l  = jj >> 2;
        const int Wl    = (l == 0) ? 64 : (l == 1) ? 32 : 16;
        const int Hl    = Wl;
        const int start = (l == 0) ? 0 : (l == 1) ? 4096 : 5120;

        const float refx = refp[(size_t)bq * 2 + 0];
        const float refy = refp[(size_t)bq * 2 + 1];
        const float lx = fminf(fmaxf(refx + off[(size_t)bq * (TP * 2) + j * 2 + 0], 0.f), 1.f) * (float)Wl - 0.5f;
        const float ly = fminf(fmaxf(refy + off[(size_t)bq * (TP * 2) + j * 2 + 1], 0.f), 1.f) * (float)Hl - 0.5f;
        const float fx0 = floorf(lx), fy0 = floorf(ly);
        const int   x0  = (int)fx0,   y0  = (int)fy0;
        const float wx1 = lx - fx0,   wy1 = ly - fy0;
        const float wx0 = 1.f - wx1,  wy0 = 1.f - wy1;
        const float aw  = s_w[j];

        #pragma unroll
        for (int k = 0; k < 4; ++k) {
            const int dx = k & 1, dy = k >> 1;
            const int xi = x0 + dx, yi = y0 + dy;
            const bool ok = (xi >= 0) & (xi < Wl) & (yi >= 0) & (yi < Hl);
            const int xc = min(max(xi, 0), Wl - 1);
            const int yc = min(max(yi, 0), Hl - 1);
            s_idx[j][k] = (start + yc * Wl + xc) * (CDIM * 2);   // bf16 rows: 512 B
            const float wxy = (dx ? wx1 : wx0) * (dy ? wy1 : wy0);
            s_twt[j][k] = ok ? aw * wxy : 0.f;
        }
    }
    __syncthreads();

    const int h  = tid >> 5;
    const int hd = tid & 31;
    const char* vb = (const char*)(v + (size_t)b * NV * CDIM + h * HD + hd);

    float acc = 0.f;
    #pragma unroll
    for (int g = 0; g < 6; ++g) {         // 6 groups x 2 points x 4 taps
        u32   raw[8];
        float wt[8];
        #pragma unroll
        for (int pp = 0; pp < 2; ++pp) {
            const int j = h * 12 + g * 2 + pp;
            const int4   ix = *reinterpret_cast<const int4*>(&s_idx[j][0]);
            const float4 tw = *reinterpret_cast<const float4*>(&s_twt[j][0]);
            raw[pp * 4 + 0] = *reinterpret_cast<const u16*>(vb + ix.x);
            raw[pp * 4 + 1] = *reinterpret_cast<const u16*>(vb + ix.y);
            raw[pp * 4 + 2] = *reinterpret_cast<const u16*>(vb + ix.z);
            raw[pp * 4 + 3] = *reinterpret_cast<const u16*>(vb + ix.w);
            wt[pp * 4 + 0] = tw.x; wt[pp * 4 + 1] = tw.y;
            wt[pp * 4 + 2] = tw.z; wt[pp * 4 + 3] = tw.w;
        }
        #pragma unroll
        for (int k = 0; k < 8; ++k)
            acc += wt[k] * __uint_as_float(raw[k] << 16);
    }

    const u16 th = bf_of(acc);
    const u16 tl = bf_of(acc - bf_back(th));
    t_hi[(size_t)bq * CDIM + tid] = th;
    t_lo[(size_t)bq * CDIM + tid] = tl;
}

// ---------------------------------------------------------------------------
// Launch
// ---------------------------------------------------------------------------
extern "C" void kernel_launch(void* const* d_in, const int* in_sizes, int n_in,
                              void* d_out, int out_size, void* d_ws, size_t ws_size,
                              hipStream_t stream)
{
    const float* query = (const float*)d_in[0];   // (B,NQ,C)
    const float* refp  = (const float*)d_in[1];   // (B,NQ,2)
    const float* value = (const float*)d_in[2];   // (B,NV,C)
    const float* Wv    = (const float*)d_in[3];   // (C,C)
    const float* bv    = (const float*)d_in[4];
    const float* Woff  = (const float*)d_in[5];   // (192,C)
    const float* boff  = (const float*)d_in[6];
    const float* Wa    = (const float*)d_in[7];   // (96,C)
    const float* ba    = (const float*)d_in[8];
    const float* Wo    = (const float*)d_in[9];   // (C,C)
    const float* bo    = (const float*)d_in[10];
    float* out = (float*)d_out;

    // ---- workspace layout (bytes), all regions 256B-aligned ----
    char* w = (char*)d_ws;
    const size_t SZ_QV = (size_t)MROWS * CDIM * 2;   // 5.5 MB per bf16 matrix
    u16* q_hi   = (u16*)(w);                  // until a-GEMM
    u16* q_lo   = (u16*)(w + SZ_QV);
    u16* val_hi = (u16*)(w + 2 * SZ_QV);      // until v-GEMM; reused as t_hi/t_lo
    u16* val_lo = (u16*)(w + 3 * SZ_QV);
    u16* v_bf16 = (u16*)(w + 4 * SZ_QV);      // gather source
    char* wp    = w + 5 * SZ_QV;
    u16* wv_hi   = (u16*)(wp);                 wp += (size_t)CDIM * CDIM * 2;
    u16* wv_lo   = (u16*)(wp);                 wp += (size_t)CDIM * CDIM * 2;
    u16* woff_hi = (u16*)(wp);                 wp += (size_t)(TP * 2) * CDIM * 2;
    u16* woff_lo = (u16*)(wp);                 wp += (size_t)(TP * 2) * CDIM * 2;
    u16* wa_hi   = (u16*)(wp);                 wp += (size_t)TP * CDIM * 2;
    u16* wa_lo   = (u16*)(wp);                 wp += (size_t)TP * CDIM * 2;
    u16* wo_hi   = (u16*)(wp);                 wp += (size_t)CDIM * CDIM * 2;
    u16* wo_lo   = (u16*)(wp);                 wp += (size_t)CDIM * CDIM * 2;
    float* ws_off = (float*)(wp);              wp += (size_t)MROWS * (TP * 2) * 4;
    float* ws_a   = (float*)(wp);
    u16* t_hi = val_hi;   // alias: value splits dead after v-GEMM
    u16* t_lo = val_lo;

    const dim3 blk(256);

    // ---- splits ----
    const int n4_qv = MROWS * CDIM / 4;       // 688128
    split_kernel<<<dim3((n4_qv + 255) / 256), blk, 0, stream>>>(value, val_hi, val_lo, n4_qv);
    split_kernel<<<dim3((n4_qv + 255) / 256), blk, 0, stream>>>(query, q_hi, q_lo, n4_qv);
    split_kernel<<<dim3(CDIM * CDIM / 4 / 256), blk, 0, stream>>>(Wv, wv_hi, wv_lo, CDIM * CDIM / 4);
    split_kernel<<<dim3(TP * 2 * CDIM / 4 / 256), blk, 0, stream>>>(Woff, woff_hi, woff_lo, TP * 2 * CDIM / 4);
    split_kernel<<<dim3(TP * CDIM / 4 / 256), blk, 0, stream>>>(Wa, wa_hi, wa_lo, TP * CDIM / 4);
    split_kernel<<<dim3(CDIM * CDIM / 4 / 256), blk, 0, stream>>>(Wo, wo_hi, wo_lo, CDIM * CDIM / 4);

    // ---- GEMMs + core ----
    // v = value @ Wv^T + bv  -> bf16
    gemm_split_kernel<1><<<dim3(MROWS / GBM, CDIM / GBN), blk, 0, stream>>>(
        val_hi, val_lo, wv_hi, wv_lo, bv, v_bf16, MROWS, CDIM, CDIM);
    // off = query @ Woff^T + boff -> fp32
    gemm_split_kernel<0><<<dim3(MROWS / GBM, (TP * 2) / GBN), blk, 0, stream>>>(
        q_hi, q_lo, woff_hi, woff_lo, boff, ws_off, MROWS, TP * 2, CDIM);
    // a = query @ Wa^T + ba -> fp32
    gemm_split_kernel<0><<<dim3(MROWS / GBM, (TP + GBN - 1) / GBN), blk, 0, stream>>>(
        q_hi, q_lo, wa_hi, wa_lo, ba, ws_a, MROWS, TP, CDIM);
    // sampling core -> t (bf16 hi/lo, overwrites value splits)
    msda_core_kernel<<<dim3(MROWS), blk, 0, stream>>>(ws_off, ws_a, refp, v_bf16, t_hi, t_lo);
    // out = t @ Wo^T + bo -> fp32
    gemm_split_kernel<0><<<dim3(MROWS / GBM, CDIM / GBN), blk, 0, stream>>>(
        t_hi, t_lo, wo_hi, wo_lo, bo, out, MROWS, CDIM, CDIM);
}

// Round 4
// 146.460 us; speedup vs baseline: 1.6737x; 1.1847x over previous
//
#include <hip/hip_runtime.h>
#include <hip/hip_bf16.h>
#include <cmath>

// Problem constants (from reference)
#define BATCH   2
#define NQ      5376
#define NV      5376
#define CDIM    256
#define HEADS   8
#define HD      32
#define LEVELS  3
#define POINTS  4
#define TP      96      // HEADS*LEVELS*POINTS
#define MROWS   (BATCH*NQ)   // 10752
#define NOFF    (TP*2)       // 192
#define NQA     (NOFF+TP)    // 288 merged off||a columns

typedef __attribute__((ext_vector_type(8))) short bf16x8;
typedef __attribute__((ext_vector_type(4))) float f32x4;
typedef unsigned short u16;
typedef unsigned int   u32;

#define AS1 __attribute__((address_space(1)))
#define AS3 __attribute__((address_space(3)))

__device__ __forceinline__ void g2lds16(const void* g, void* l) {
    // async global->LDS, 16B per lane; LDS dest = wave-uniform base + lane*16
    __builtin_amdgcn_global_load_lds((const AS1 void*)g, (AS3 void*)l, 16, 0, 0);
}

__device__ __forceinline__ u16 bf_of(float f) {
    union { __hip_bfloat16 h; u16 s; } u;
    u.h = __float2bfloat16(f);
    return u.s;
}
__device__ __forceinline__ float bf_back(u16 s) {
    return __uint_as_float((u32)s << 16);
}

// ---------------------------------------------------------------------------
// Fused split of value + query: fp32 -> bf16 hi + bf16 lo(residual).
// First n4 float4's = value, next n4 = query.
// ---------------------------------------------------------------------------
__global__ __launch_bounds__(256) void split_vq_kernel(
    const float* __restrict__ value, const float* __restrict__ query,
    u16* __restrict__ vhi, u16* __restrict__ vlo,
    u16* __restrict__ qhi, u16* __restrict__ qlo, int n4)
{
    int i = blockIdx.x * 256 + threadIdx.x;
    const float* src; u16* dh; u16* dl;
    if (i < n4) { src = value; dh = vhi; dl = vlo; }
    else        { src = query; dh = qhi; dl = qlo; i -= n4; }
    const float4 v = reinterpret_cast<const float4*>(src)[i];
    ushort4 h, l;
    h.x = bf_of(v.x); l.x = bf_of(v.x - bf_back(h.x));
    h.y = bf_of(v.y); l.y = bf_of(v.y - bf_back(h.y));
    h.z = bf_of(v.z); l.z = bf_of(v.z - bf_back(h.z));
    h.w = bf_of(v.w); l.w = bf_of(v.w - bf_back(h.w));
    reinterpret_cast<ushort4*>(dh)[i] = h;
    reinterpret_cast<ushort4*>(dl)[i] = l;
}

// ---------------------------------------------------------------------------
// Fused split of all weights: Wv (256x256), merged Woff||Wa (288x256), Wo.
// float4 index ranges: [0,16384) Wv, [16384,34816) merged, [34816,51200) Wo.
// Grid = 200 blocks x 256 exactly.
// ---------------------------------------------------------------------------
__global__ __launch_bounds__(256) void split_w_kernel(
    const float* __restrict__ Wv, const float* __restrict__ Woff,
    const float* __restrict__ Wa, const float* __restrict__ Wo,
    u16* __restrict__ wv_hi, u16* __restrict__ wv_lo,
    u16* __restrict__ wqa_hi, u16* __restrict__ wqa_lo,
    u16* __restrict__ wo_hi, u16* __restrict__ wo_lo)
{
    const int i = blockIdx.x * 256 + threadIdx.x;
    const float* src; u16* dh; u16* dl; int j;
    if (i < 16384) {
        j = i; src = Wv + (size_t)j * 4; dh = wv_hi; dl = wv_lo;
    } else if (i < 34816) {
        j = i - 16384;
        const int row = j >> 6, c4 = j & 63;
        src = (row < NOFF) ? (Woff + (size_t)row * CDIM + c4 * 4)
                           : (Wa + (size_t)(row - NOFF) * CDIM + c4 * 4);
        dh = wqa_hi; dl = wqa_lo;
    } else {
        j = i - 34816; src = Wo + (size_t)j * 4; dh = wo_hi; dl = wo_lo;
    }
    const float4 v = *reinterpret_cast<const float4*>(src);
    ushort4 h, l;
    h.x = bf_of(v.x); l.x = bf_of(v.x - bf_back(h.x));
    h.y = bf_of(v.y); l.y = bf_of(v.y - bf_back(h.y));
    h.z = bf_of(v.z); l.z = bf_of(v.z - bf_back(h.z));
    h.w = bf_of(v.w); l.w = bf_of(v.w - bf_back(h.w));
    reinterpret_cast<ushort4*>(dh)[j] = h;
    reinterpret_cast<ushort4*>(dl)[j] = l;
}

// ---------------------------------------------------------------------------
// Split-bf16 MFMA GEMM: C = A @ W^T + bias via Ah*Bh + Ah*Bl + Al*Bh.
// Tile 64x64x32, 256 threads = 4 waves (2x2 of 32x32 wave tiles).
// global_load_lds x16 staging; LDS 16 KB -> many blocks/CU.
// Requires M % 64 == 0, K % 32 == 0. N guarded.
// MODE 0: fp32 out (ld=N). MODE 1: bf16 out. MODE 2: dual fp32 out,
//   n<192 -> C1 (ld 192, bias1), else C2 (ld 96, bias2).
// ---------------------------------------------------------------------------
#define GBM 64
#define GBN 64
#define GBK 32

template <int MODE>
__global__ __launch_bounds__(256) void gemm_split_kernel(
    const u16* __restrict__ Ah, const u16* __restrict__ Al,
    const u16* __restrict__ Bh, const u16* __restrict__ Bl,
    const float* __restrict__ bias, const float* __restrict__ bias2,
    void* __restrict__ Cout, void* __restrict__ Cout2,
    int M, int N, int K)
{
    __shared__ u16 sAh[GBM * GBK];   // 4 KB each
    __shared__ u16 sAl[GBM * GBK];
    __shared__ u16 sBh[GBN * GBK];
    __shared__ u16 sBl[GBN * GBK];

    const int m0 = blockIdx.x * GBM;
    const int n0 = blockIdx.y * GBN;
    const int tid  = threadIdx.x;
    const int lane = tid & 63;
    const int wave = tid >> 6;
    const int wr   = wave & 1;     // m offset 32*wr
    const int wc   = wave >> 1;    // n offset 32*wc
    const int qm   = lane & 15;
    const int quad = lane >> 4;

    f32x4 acc[2][2];
    #pragma unroll
    for (int i = 0; i < 2; ++i)
        #pragma unroll
        for (int j = 0; j < 2; ++j)
            acc[i][j] = (f32x4){0.f, 0.f, 0.f, 0.f};

    // staging: each wave stages one 16-row chunk of each of the 4 buffers
    const int srow = (wave << 4) + (lane >> 2);   // tile row
    const int sk   = (lane & 3) * 8;              // bf16 k-offset
    const int brc  = min(n0 + srow, N - 1);       // clamp OOB B rows

    for (int k0 = 0; k0 < K; k0 += GBK) {
        const size_t ga = (size_t)(m0 + srow) * K + k0 + sk;
        const size_t gb = (size_t)brc * K + k0 + sk;
        g2lds16(Ah + ga, sAh + wave * 512);
        g2lds16(Al + ga, sAl + wave * 512);
        g2lds16(Bh + gb, sBh + wave * 512);
        g2lds16(Bl + gb, sBl + wave * 512);
        __syncthreads();

        bf16x8 fah[2], fal[2], fbh[2], fbl[2];
        #pragma unroll
        for (int x = 0; x < 2; ++x) {
            const int rm = wr * 32 + x * 16 + qm;
            const int rn = wc * 32 + x * 16 + qm;
            fah[x] = *reinterpret_cast<const bf16x8*>(&sAh[rm * GBK + quad * 8]);
            fal[x] = *reinterpret_cast<const bf16x8*>(&sAl[rm * GBK + quad * 8]);
            fbh[x] = *reinterpret_cast<const bf16x8*>(&sBh[rn * GBK + quad * 8]);
            fbl[x] = *reinterpret_cast<const bf16x8*>(&sBl[rn * GBK + quad * 8]);
        }
        #pragma unroll
        for (int mi = 0; mi < 2; ++mi)
            #pragma unroll
            for (int ni = 0; ni < 2; ++ni) {
                acc[mi][ni] = __builtin_amdgcn_mfma_f32_16x16x32_bf16(
                    fah[mi], fbh[ni], acc[mi][ni], 0, 0, 0);
                acc[mi][ni] = __builtin_amdgcn_mfma_f32_16x16x32_bf16(
                    fah[mi], fbl[ni], acc[mi][ni], 0, 0, 0);
                acc[mi][ni] = __builtin_amdgcn_mfma_f32_16x16x32_bf16(
                    fal[mi], fbh[ni], acc[mi][ni], 0, 0, 0);
            }
        __syncthreads();
    }

    // epilogue: C/D layout col = lane&15 (n), row = quad*4 + reg (m)
    #pragma unroll
    for (int mi = 0; mi < 2; ++mi) {
        #pragma unroll
        for (int ni = 0; ni < 2; ++ni) {
            const int n = n0 + wc * 32 + ni * 16 + qm;
            if (n >= N) continue;
            float bn;
            if (MODE == 2) bn = (n < NOFF) ? bias[n] : bias2[n - NOFF];
            else           bn = bias[n];
            #pragma unroll
            for (int r = 0; r < 4; ++r) {
                const int m = m0 + wr * 32 + mi * 16 + quad * 4 + r;
                const float val = acc[mi][ni][r] + bn;
                if (MODE == 0)
                    reinterpret_cast<float*>(Cout)[(size_t)m * N + n] = val;
                else if (MODE == 1)
                    reinterpret_cast<u16*>(Cout)[(size_t)m * N + n] = bf_of(val);
                else {
                    if (n < NOFF)
                        reinterpret_cast<float*>(Cout)[(size_t)m * NOFF + n] = val;
                    else
                        reinterpret_cast<float*>(Cout2)[(size_t)m * TP + (n - NOFF)] = val;
                }
            }
        }
    }
}

// ---------------------------------------------------------------------------
// MSDA core v4: 2 queries per block, 2 channels per thread (dword gathers).
// Phase A (per query-half: 96 of 128 threads): softmax + tap offsets/weights
// into LDS. Phase B: 8 heads x 16 channel-pairs, 48 dword loads per thread
// batched in groups of 8. Output t as bf16 hi/lo (packed u32 stores).
// ---------------------------------------------------------------------------
__global__ __launch_bounds__(256) void msda_core_kernel(
    const float* __restrict__ off,   // (B*NQ, 192)
    const float* __restrict__ alog,  // (B*NQ, 96)
    const float* __restrict__ refp,  // (B*NQ, 2)
    const u16*   __restrict__ v,     // (B, NV, 256) bf16
    u16* __restrict__ t_hi,          // (B*NQ, 256) bf16
    u16* __restrict__ t_lo)          // (B*NQ, 256) bf16
{
    const int tid  = threadIdx.x;
    const int half = tid >> 7;          // which of the 2 queries
    const int ht   = tid & 127;
    const int bq   = blockIdx.x * 2 + half;
    const int b    = bq / NQ;

    __shared__ float s_w[2][TP];
    __shared__ int   s_idx[2][TP][4];
    __shared__ float s_twt[2][TP][4];

    if (ht < TP) s_w[half][ht] = alog[(size_t)bq * TP + ht];
    __syncthreads();

    if (ht < HEADS) {
        float mx = -1e30f;
        #pragma unroll
        for (int i = 0; i < 12; ++i) mx = fmaxf(mx, s_w[half][ht * 12 + i]);
        float e[12];
        float sum = 0.f;
        #pragma unroll
        for (int i = 0; i < 12; ++i) {
            e[i] = expf(s_w[half][ht * 12 + i] - mx);
            sum += e[i];
        }
        const float inv = 1.f / sum;
        #pragma unroll
        for (int i = 0; i < 12; ++i) s_w[half][ht * 12 + i] = e[i] * inv;
    }
    __syncthreads();

    if (ht < TP) {
        const int j  = ht;
        const int jj = j % 12;
        const int l  = jj >> 2;
        const int Wl    = (l == 0) ? 64 : (l == 1) ? 32 : 16;
        const int start = (l == 0) ? 0 : (l == 1) ? 4096 : 5120;

        const float refx = refp[(size_t)bq * 2 + 0];
        const float refy = refp[(size_t)bq * 2 + 1];
        const float lx = fminf(fmaxf(refx + off[(size_t)bq * NOFF + j * 2 + 0], 0.f), 1.f) * (float)Wl - 0.5f;
        const float ly = fminf(fmaxf(refy + off[(size_t)bq * NOFF + j * 2 + 1], 0.f), 1.f) * (float)Wl - 0.5f;
        const float fx0 = floorf(lx), fy0 = floorf(ly);
        const int   x0  = (int)fx0,   y0  = (int)fy0;
        const float wx1 = lx - fx0,   wy1 = ly - fy0;
        const float wx0 = 1.f - wx1,  wy0 = 1.f - wy1;
        const float aw  = s_w[half][j];

        #pragma unroll
        for (int k = 0; k < 4; ++k) {
            const int dx = k & 1, dy = k >> 1;
            const int xi = x0 + dx, yi = y0 + dy;
            const bool ok = (xi >= 0) & (xi < Wl) & (yi >= 0) & (yi < Wl);
            const int xc = min(max(xi, 0), Wl - 1);
            const int yc = min(max(yi, 0), Wl - 1);
            s_idx[half][j][k] = (start + yc * Wl + xc) * (CDIM * 2);  // byte off, 512B rows
            const float wxy = (dx ? wx1 : wx0) * (dy ? wy1 : wy0);
            s_twt[half][j][k] = ok ? aw * wxy : 0.f;
        }
    }
    __syncthreads();

    const int h  = ht >> 4;    // 0..7
    const int cp = ht & 15;    // channel pair -> channels 2cp, 2cp+1
    const char* vb = (const char*)(v + (size_t)b * NV * CDIM + h * HD + cp * 2);

    float accx = 0.f, accy = 0.f;
    #pragma unroll
    for (int g = 0; g < 6; ++g) {        // 6 groups x 2 points x 4 taps
        u32   raw[8];
        float wt[8];
        #pragma unroll
        for (int pp = 0; pp < 2; ++pp) {
            const int j = h * 12 + g * 2 + pp;
            const int4   ix = *reinterpret_cast<const int4*>(&s_idx[half][j][0]);
            const float4 tw = *reinterpret_cast<const float4*>(&s_twt[half][j][0]);
            raw[pp * 4 + 0] = *reinterpret_cast<const u32*>(vb + ix.x);
            raw[pp * 4 + 1] = *reinterpret_cast<const u32*>(vb + ix.y);
            raw[pp * 4 + 2] = *reinterpret_cast<const u32*>(vb + ix.z);
            raw[pp * 4 + 3] = *reinterpret_cast<const u32*>(vb + ix.w);
            wt[pp * 4 + 0] = tw.x; wt[pp * 4 + 1] = tw.y;
            wt[pp * 4 + 2] = tw.z; wt[pp * 4 + 3] = tw.w;
        }
        #pragma unroll
        for (int k = 0; k < 8; ++k) {
            accx += wt[k] * __uint_as_float(raw[k] << 16);
            accy += wt[k] * __uint_as_float(raw[k] & 0xffff0000u);
        }
    }

    const u16 th0 = bf_of(accx), tl0 = bf_of(accx - bf_back(th0));
    const u16 th1 = bf_of(accy), tl1 = bf_of(accy - bf_back(th1));
    const size_t oi = (size_t)bq * (CDIM / 2) + h * 16 + cp;
    reinterpret_cast<u32*>(t_hi)[oi] = (u32)th0 | ((u32)th1 << 16);
    reinterpret_cast<u32*>(t_lo)[oi] = (u32)tl0 | ((u32)tl1 << 16);
}

// ---------------------------------------------------------------------------
// Launch
// ---------------------------------------------------------------------------
extern "C" void kernel_launch(void* const* d_in, const int* in_sizes, int n_in,
                              void* d_out, int out_size, void* d_ws, size_t ws_size,
                              hipStream_t stream)
{
    const float* query = (const float*)d_in[0];   // (B,NQ,C)
    const float* refp  = (const float*)d_in[1];   // (B,NQ,2)
    const float* value = (const float*)d_in[2];   // (B,NV,C)
    const float* Wv    = (const float*)d_in[3];   // (C,C)
    const float* bv    = (const float*)d_in[4];
    const float* Woff  = (const float*)d_in[5];   // (192,C)
    const float* boff  = (const float*)d_in[6];
    const float* Wa    = (const float*)d_in[7];   // (96,C)
    const float* ba    = (const float*)d_in[8];
    const float* Wo    = (const float*)d_in[9];   // (C,C)
    const float* bo    = (const float*)d_in[10];
    float* out = (float*)d_out;

    // ---- workspace layout ----
    char* w = (char*)d_ws;
    const size_t SZ_QV = (size_t)MROWS * CDIM * 2;   // 5.5 MB per bf16 matrix
    u16* q_hi   = (u16*)(w);
    u16* q_lo   = (u16*)(w + SZ_QV);
    u16* val_hi = (u16*)(w + 2 * SZ_QV);      // dead after v-GEMM -> reused as t
    u16* val_lo = (u16*)(w + 3 * SZ_QV);
    u16* v_bf16 = (u16*)(w + 4 * SZ_QV);      // gather source
    char* wp    = w + 5 * SZ_QV;
    u16* wv_hi  = (u16*)(wp);                  wp += (size_t)CDIM * CDIM * 2;
    u16* wv_lo  = (u16*)(wp);                  wp += (size_t)CDIM * CDIM * 2;
    u16* wqa_hi = (u16*)(wp);                  wp += (size_t)NQA * CDIM * 2;
    u16* wqa_lo = (u16*)(wp);                  wp += (size_t)NQA * CDIM * 2;
    u16* wo_hi  = (u16*)(wp);                  wp += (size_t)CDIM * CDIM * 2;
    u16* wo_lo  = (u16*)(wp);                  wp += (size_t)CDIM * CDIM * 2;
    float* ws_off = (float*)(wp);              wp += (size_t)MROWS * NOFF * 4;
    float* ws_a   = (float*)(wp);
    u16* t_hi = val_hi;
    u16* t_lo = val_lo;

    const dim3 blk(256);
    const int n4_qv = MROWS * CDIM / 4;       // 688128

    // ---- splits (2 dispatches) ----
    split_vq_kernel<<<dim3(2 * n4_qv / 256), blk, 0, stream>>>(
        value, query, val_hi, val_lo, q_hi, q_lo, n4_qv);
    split_w_kernel<<<dim3(200), blk, 0, stream>>>(
        Wv, Woff, Wa, Wo, wv_hi, wv_lo, wqa_hi, wqa_lo, wo_hi, wo_lo);

    // ---- GEMMs + core ----
    // v = value @ Wv^T + bv  -> bf16
    gemm_split_kernel<1><<<dim3(MROWS / GBM, CDIM / GBN), blk, 0, stream>>>(
        val_hi, val_lo, wv_hi, wv_lo, bv, nullptr, v_bf16, nullptr,
        MROWS, CDIM, CDIM);
    // [off | a] = query @ [Woff;Wa]^T + [boff;ba] -> dual fp32
    gemm_split_kernel<2><<<dim3(MROWS / GBM, (NQA + GBN - 1) / GBN), blk, 0, stream>>>(
        q_hi, q_lo, wqa_hi, wqa_lo, boff, ba, ws_off, ws_a,
        MROWS, NQA, CDIM);
    // sampling core -> t (bf16 hi/lo)
    msda_core_kernel<<<dim3(MROWS / 2), blk, 0, stream>>>(
        ws_off, ws_a, refp, v_bf16, t_hi, t_lo);
    // out = t @ Wo^T + bo -> fp32
    gemm_split_kernel<0><<<dim3(MROWS / GBM, CDIM / GBN), blk, 0, stream>>>(
        t_hi, t_lo, wo_hi, wo_lo, bo, nullptr, out, nullptr,
        MROWS, CDIM, CDIM);
}

// Round 5
// 141.940 us; speedup vs baseline: 1.7270x; 1.0318x over previous
//
#include <hip/hip_runtime.h>
#include <hip/hip_bf16.h>
#include <cmath>

// Problem constants (from reference)
#define BATCH   2
#define NQ      5376
#define NV      5376
#define CDIM    256
#define HEADS   8
#define HD      32
#define LEVELS  3
#define POINTS  4
#define TP      96      // HEADS*LEVELS*POINTS
#define MROWS   (BATCH*NQ)   // 10752
#define NOFF    (TP*2)       // 192
#define NQA     (NOFF+TP)    // 288 merged off||a columns

typedef __attribute__((ext_vector_type(8))) short bf16x8;
typedef __attribute__((ext_vector_type(4))) float f32x4;
typedef unsigned short u16;
typedef unsigned int   u32;

#define AS1 __attribute__((address_space(1)))
#define AS3 __attribute__((address_space(3)))

__device__ __forceinline__ void g2lds16(const void* g, void* l) {
    // async global->LDS, 16B per lane; LDS dest = wave-uniform base + lane*16
    __builtin_amdgcn_global_load_lds((const AS1 void*)g, (AS3 void*)l, 16, 0, 0);
}

__device__ __forceinline__ u16 bf_of(float f) {
    union { __hip_bfloat16 h; u16 s; } u;
    u.h = __float2bfloat16(f);
    return u.s;
}
__device__ __forceinline__ float bf_back(u16 s) {
    return __uint_as_float((u32)s << 16);
}

// ---------------------------------------------------------------------------
// Fused split of value + query. value -> hi+lo(residual); query -> hi only
// (qa-GEMM runs pure bf16). First n4 float4's = value, next n4 = query.
// ---------------------------------------------------------------------------
__global__ __launch_bounds__(256) void split_vq_kernel(
    const float* __restrict__ value, const float* __restrict__ query,
    u16* __restrict__ vhi, u16* __restrict__ vlo,
    u16* __restrict__ qhi, int n4)
{
    int i = blockIdx.x * 256 + threadIdx.x;
    const float* src; u16* dh; u16* dl;
    if (i < n4) { src = value; dh = vhi; dl = vlo; }
    else        { src = query; dh = qhi; dl = nullptr; i -= n4; }
    const float4 v = reinterpret_cast<const float4*>(src)[i];
    ushort4 h;
    h.x = bf_of(v.x); h.y = bf_of(v.y); h.z = bf_of(v.z); h.w = bf_of(v.w);
    reinterpret_cast<ushort4*>(dh)[i] = h;
    if (dl) {
        ushort4 l;
        l.x = bf_of(v.x - bf_back(h.x));
        l.y = bf_of(v.y - bf_back(h.y));
        l.z = bf_of(v.z - bf_back(h.z));
        l.w = bf_of(v.w - bf_back(h.w));
        reinterpret_cast<ushort4*>(dl)[i] = l;
    }
}

// ---------------------------------------------------------------------------
// Fused split of all weights: Wv hi+lo, merged Woff||Wa hi only, Wo hi+lo.
// float4 index ranges: [0,16384) Wv, [16384,34816) merged, [34816,51200) Wo.
// Grid = 200 blocks x 256 exactly.
// ---------------------------------------------------------------------------
__global__ __launch_bounds__(256) void split_w_kernel(
    const float* __restrict__ Wv, const float* __restrict__ Woff,
    const float* __restrict__ Wa, const float* __restrict__ Wo,
    u16* __restrict__ wv_hi, u16* __restrict__ wv_lo,
    u16* __restrict__ wqa_hi,
    u16* __restrict__ wo_hi, u16* __restrict__ wo_lo)
{
    const int i = blockIdx.x * 256 + threadIdx.x;
    const float* src; u16* dh; u16* dl; int j;
    if (i < 16384) {
        j = i; src = Wv + (size_t)j * 4; dh = wv_hi; dl = wv_lo;
    } else if (i < 34816) {
        j = i - 16384;
        const int row = j >> 6, c4 = j & 63;
        src = (row < NOFF) ? (Woff + (size_t)row * CDIM + c4 * 4)
                           : (Wa + (size_t)(row - NOFF) * CDIM + c4 * 4);
        dh = wqa_hi; dl = nullptr;
    } else {
        j = i - 34816; src = Wo + (size_t)j * 4; dh = wo_hi; dl = wo_lo;
    }
    const float4 v = *reinterpret_cast<const float4*>(src);
    ushort4 h;
    h.x = bf_of(v.x); h.y = bf_of(v.y); h.z = bf_of(v.z); h.w = bf_of(v.w);
    reinterpret_cast<ushort4*>(dh)[j] = h;
    if (dl) {
        ushort4 l;
        l.x = bf_of(v.x - bf_back(h.x));
        l.y = bf_of(v.y - bf_back(h.y));
        l.z = bf_of(v.z - bf_back(h.z));
        l.w = bf_of(v.w - bf_back(h.w));
        reinterpret_cast<ushort4*>(dl)[j] = l;
    }
}

// ---------------------------------------------------------------------------
// bf16 MFMA GEMM: C = A @ W^T + bias.
// NPROD: 1 = AhBh; 2 = + AlBh; 3 = + AhBl (split-precision ladder).
// Tile 64x64x32, 256 threads = 4 waves (2x2 of 32x32). global_load_lds x16
// staging. Requires M % 64 == 0, K % 32 == 0. N guarded.
// MODE 0: fp32 out (ld=N).
// MODE 1: bf16 out in HEAD-MAJOR value layout (B, HEADS, NV, HD).
// MODE 2: dual fp32 out: n<192 -> C1 (ld 192, bias), else C2 (ld 96, bias2).
// ---------------------------------------------------------------------------
#define GBM 64
#define GBN 64
#define GBK 32

template <int NPROD, int MODE>
__global__ __launch_bounds__(256) void gemm_split_kernel(
    const u16* __restrict__ Ah, const u16* __restrict__ Al,
    const u16* __restrict__ Bh, const u16* __restrict__ Bl,
    const float* __restrict__ bias, const float* __restrict__ bias2,
    void* __restrict__ Cout, void* __restrict__ Cout2,
    int M, int N, int K)
{
    __shared__ u16 sAh[GBM * GBK];   // 4 KB each
    __shared__ u16 sAl[GBM * GBK];
    __shared__ u16 sBh[GBN * GBK];
    __shared__ u16 sBl[GBN * GBK];

    const int m0 = blockIdx.x * GBM;
    const int n0 = blockIdx.y * GBN;
    const int tid  = threadIdx.x;
    const int lane = tid & 63;
    const int wave = tid >> 6;
    const int wr   = wave & 1;     // m offset 32*wr
    const int wc   = wave >> 1;    // n offset 32*wc
    const int qm   = lane & 15;
    const int quad = lane >> 4;

    f32x4 acc[2][2];
    #pragma unroll
    for (int i = 0; i < 2; ++i)
        #pragma unroll
        for (int j = 0; j < 2; ++j)
            acc[i][j] = (f32x4){0.f, 0.f, 0.f, 0.f};

    // staging: each wave stages one 16-row chunk of each staged buffer
    const int srow = (wave << 4) + (lane >> 2);   // tile row
    const int sk   = (lane & 3) * 8;              // bf16 k-offset
    const int brc  = min(n0 + srow, N - 1);       // clamp OOB B rows

    for (int k0 = 0; k0 < K; k0 += GBK) {
        const size_t ga = (size_t)(m0 + srow) * K + k0 + sk;
        const size_t gb = (size_t)brc * K + k0 + sk;
        g2lds16(Ah + ga, sAh + wave * 512);
        if (NPROD >= 2) g2lds16(Al + ga, sAl + wave * 512);
        g2lds16(Bh + gb, sBh + wave * 512);
        if (NPROD >= 3) g2lds16(Bl + gb, sBl + wave * 512);
        __syncthreads();

        bf16x8 fah[2], fal[2], fbh[2], fbl[2];
        #pragma unroll
        for (int x = 0; x < 2; ++x) {
            const int rm = wr * 32 + x * 16 + qm;
            const int rn = wc * 32 + x * 16 + qm;
            fah[x] = *reinterpret_cast<const bf16x8*>(&sAh[rm * GBK + quad * 8]);
            fbh[x] = *reinterpret_cast<const bf16x8*>(&sBh[rn * GBK + quad * 8]);
            if (NPROD >= 2)
                fal[x] = *reinterpret_cast<const bf16x8*>(&sAl[rm * GBK + quad * 8]);
            if (NPROD >= 3)
                fbl[x] = *reinterpret_cast<const bf16x8*>(&sBl[rn * GBK + quad * 8]);
        }
        #pragma unroll
        for (int mi = 0; mi < 2; ++mi)
            #pragma unroll
            for (int ni = 0; ni < 2; ++ni) {
                acc[mi][ni] = __builtin_amdgcn_mfma_f32_16x16x32_bf16(
                    fah[mi], fbh[ni], acc[mi][ni], 0, 0, 0);
                if (NPROD >= 2)
                    acc[mi][ni] = __builtin_amdgcn_mfma_f32_16x16x32_bf16(
                        fal[mi], fbh[ni], acc[mi][ni], 0, 0, 0);
                if (NPROD >= 3)
                    acc[mi][ni] = __builtin_amdgcn_mfma_f32_16x16x32_bf16(
                        fah[mi], fbl[ni], acc[mi][ni], 0, 0, 0);
            }
        __syncthreads();
    }

    // epilogue: C/D layout col = lane&15 (n), row = quad*4 + reg (m)
    #pragma unroll
    for (int mi = 0; mi < 2; ++mi) {
        #pragma unroll
        for (int ni = 0; ni < 2; ++ni) {
            const int n = n0 + wc * 32 + ni * 16 + qm;
            if (n >= N) continue;
            float bn;
            if (MODE == 2) bn = (n < NOFF) ? bias[n] : bias2[n - NOFF];
            else           bn = bias[n];
            #pragma unroll
            for (int r = 0; r < 4; ++r) {
                const int m = m0 + wr * 32 + mi * 16 + quad * 4 + r;
                const float val = acc[mi][ni][r] + bn;
                if (MODE == 0) {
                    reinterpret_cast<float*>(Cout)[(size_t)m * N + n] = val;
                } else if (MODE == 1) {
                    // head-major (B, HEADS, NV, HD)
                    const int b = m / NV, rr = m - b * NV;
                    const int h = n >> 5, c = n & 31;
                    reinterpret_cast<u16*>(Cout)[
                        (((size_t)b * HEADS + h) * NV + rr) * HD + c] = bf_of(val);
                } else {
                    if (n < NOFF)
                        reinterpret_cast<float*>(Cout)[(size_t)m * NOFF + n] = val;
                    else
                        reinterpret_cast<float*>(Cout2)[(size_t)m * TP + (n - NOFF)] = val;
                }
            }
        }
    }
}

// ---------------------------------------------------------------------------
// MSDA core v5: 2 queries/block. v is head-major bf16 (B, HEADS, NV, HD) so
// each corner's 32 channels are 64 contiguous bytes. Per query: 128 threads =
// 8 heads x 8 channel-quads x 2 replicas; each replica gathers 6 of 12 taps
// with dwordx2 loads (24 loads/thread), then shfl_xor(8) combines replicas.
// ---------------------------------------------------------------------------
__global__ __launch_bounds__(256) void msda_core_kernel(
    const float* __restrict__ off,   // (B*NQ, 192)
    const float* __restrict__ alog,  // (B*NQ, 96)
    const float* __restrict__ refp,  // (B*NQ, 2)
    const u16*   __restrict__ v,     // (B, HEADS, NV, HD) bf16
    u16* __restrict__ t_hi,          // (B*NQ, 256) bf16
    u16* __restrict__ t_lo)          // (B*NQ, 256) bf16
{
    const int tid  = threadIdx.x;
    const int half = tid >> 7;          // which of the 2 queries
    const int ht   = tid & 127;
    const int bq   = blockIdx.x * 2 + half;
    const int b    = bq / NQ;

    __shared__ float s_w[2][TP];
    __shared__ int   s_idx[2][TP][4];   // spatial*64 byte offsets in head plane
    __shared__ float s_twt[2][TP][4];

    if (ht < TP) s_w[half][ht] = alog[(size_t)bq * TP + ht];
    __syncthreads();

    if (ht < HEADS) {
        float mx = -1e30f;
        #pragma unroll
        for (int i = 0; i < 12; ++i) mx = fmaxf(mx, s_w[half][ht * 12 + i]);
        float e[12];
        float sum = 0.f;
        #pragma unroll
        for (int i = 0; i < 12; ++i) {
            e[i] = expf(s_w[half][ht * 12 + i] - mx);
            sum += e[i];
        }
        const float inv = 1.f / sum;
        #pragma unroll
        for (int i = 0; i < 12; ++i) s_w[half][ht * 12 + i] = e[i] * inv;
    }
    __syncthreads();

    if (ht < TP) {
        const int j  = ht;
        const int jj = j % 12;
        const int l  = jj >> 2;
        const int Wl    = (l == 0) ? 64 : (l == 1) ? 32 : 16;
        const int start = (l == 0) ? 0 : (l == 1) ? 4096 : 5120;

        const float refx = refp[(size_t)bq * 2 + 0];
        const float refy = refp[(size_t)bq * 2 + 1];
        const float lx = fminf(fmaxf(refx + off[(size_t)bq * NOFF + j * 2 + 0], 0.f), 1.f) * (float)Wl - 0.5f;
        const float ly = fminf(fmaxf(refy + off[(size_t)bq * NOFF + j * 2 + 1], 0.f), 1.f) * (float)Wl - 0.5f;
        const float fx0 = floorf(lx), fy0 = floorf(ly);
        const int   x0  = (int)fx0,   y0  = (int)fy0;
        const float wx1 = lx - fx0,   wy1 = ly - fy0;
        const float wx0 = 1.f - wx1,  wy0 = 1.f - wy1;
        const float aw  = s_w[half][j];

        #pragma unroll
        for (int k = 0; k < 4; ++k) {
            const int dx = k & 1, dy = k >> 1;
            const int xi = x0 + dx, yi = y0 + dy;
            const bool ok = (xi >= 0) & (xi < Wl) & (yi >= 0) & (yi < Wl);
            const int xc = min(max(xi, 0), Wl - 1);
            const int yc = min(max(yi, 0), Wl - 1);
            s_idx[half][j][k] = (start + yc * Wl + xc) * (HD * 2);  // 64 B rows
            const float wxy = (dx ? wx1 : wx0) * (dy ? wy1 : wy0);
            s_twt[half][j][k] = ok ? aw * wxy : 0.f;
        }
    }
    __syncthreads();

    const int h   = ht >> 4;     // 0..7
    const int sub = ht & 15;
    const int q   = sub & 7;     // channel quad: channels 4q..4q+3
    const int rep = sub >> 3;    // replica 0/1 -> taps [6r, 6r+6)
    const char* vb = (const char*)v + (((size_t)b * HEADS + h) * NV) * (HD * 2) + q * 8;

    float acc0 = 0.f, acc1 = 0.f, acc2 = 0.f, acc3 = 0.f;
    #pragma unroll
    for (int g = 0; g < 3; ++g) {        // 3 groups x 2 taps x 4 corners = 8 loads
        uint2 raw[8];
        float wt[8];
        #pragma unroll
        for (int pp = 0; pp < 2; ++pp) {
            const int j = h * 12 + rep * 6 + g * 2 + pp;
            const int4   ix = *reinterpret_cast<const int4*>(&s_idx[half][j][0]);
            const float4 tw = *reinterpret_cast<const float4*>(&s_twt[half][j][0]);
            raw[pp * 4 + 0] = *reinterpret_cast<const uint2*>(vb + ix.x);
            raw[pp * 4 + 1] = *reinterpret_cast<const uint2*>(vb + ix.y);
            raw[pp * 4 + 2] = *reinterpret_cast<const uint2*>(vb + ix.z);
            raw[pp * 4 + 3] = *reinterpret_cast<const uint2*>(vb + ix.w);
            wt[pp * 4 + 0] = tw.x; wt[pp * 4 + 1] = tw.y;
            wt[pp * 4 + 2] = tw.z; wt[pp * 4 + 3] = tw.w;
        }
        #pragma unroll
        for (int k = 0; k < 8; ++k) {
            acc0 += wt[k] * __uint_as_float(raw[k].x << 16);
            acc1 += wt[k] * __uint_as_float(raw[k].x & 0xffff0000u);
            acc2 += wt[k] * __uint_as_float(raw[k].y << 16);
            acc3 += wt[k] * __uint_as_float(raw[k].y & 0xffff0000u);
        }
    }

    // combine the two tap-replicas (lanes differ in bit 3)
    acc0 += __shfl_xor(acc0, 8);
    acc1 += __shfl_xor(acc1, 8);
    acc2 += __shfl_xor(acc2, 8);
    acc3 += __shfl_xor(acc3, 8);

    if (rep == 0) {
        ushort4 hh, ll;
        hh.x = bf_of(acc0); ll.x = bf_of(acc0 - bf_back(hh.x));
        hh.y = bf_of(acc1); ll.y = bf_of(acc1 - bf_back(hh.y));
        hh.z = bf_of(acc2); ll.z = bf_of(acc2 - bf_back(hh.z));
        hh.w = bf_of(acc3); ll.w = bf_of(acc3 - bf_back(hh.w));
        const size_t base = (size_t)bq * CDIM + h * HD + q * 4;
        *reinterpret_cast<ushort4*>(t_hi + base) = hh;
        *reinterpret_cast<ushort4*>(t_lo + base) = ll;
    }
}

// ---------------------------------------------------------------------------
// Launch
// ---------------------------------------------------------------------------
extern "C" void kernel_launch(void* const* d_in, const int* in_sizes, int n_in,
                              void* d_out, int out_size, void* d_ws, size_t ws_size,
                              hipStream_t stream)
{
    const float* query = (const float*)d_in[0];   // (B,NQ,C)
    const float* refp  = (const float*)d_in[1];   // (B,NQ,2)
    const float* value = (const float*)d_in[2];   // (B,NV,C)
    const float* Wv    = (const float*)d_in[3];   // (C,C)
    const float* bv    = (const float*)d_in[4];
    const float* Woff  = (const float*)d_in[5];   // (192,C)
    const float* boff  = (const float*)d_in[6];
    const float* Wa    = (const float*)d_in[7];   // (96,C)
    const float* ba    = (const float*)d_in[8];
    const float* Wo    = (const float*)d_in[9];   // (C,C)
    const float* bo    = (const float*)d_in[10];
    float* out = (float*)d_out;

    // ---- workspace layout ----
    char* w = (char*)d_ws;
    const size_t SZ_QV = (size_t)MROWS * CDIM * 2;   // 5.5 MB per bf16 matrix
    u16* q_hi   = (u16*)(w);
    u16* val_hi = (u16*)(w + 1 * SZ_QV);      // dead after v-GEMM -> reused as t
    u16* val_lo = (u16*)(w + 2 * SZ_QV);
    u16* v_bf16 = (u16*)(w + 3 * SZ_QV);      // gather source, head-major
    char* wp    = w + 4 * SZ_QV;
    u16* wv_hi  = (u16*)(wp);                  wp += (size_t)CDIM * CDIM * 2;
    u16* wv_lo  = (u16*)(wp);                  wp += (size_t)CDIM * CDIM * 2;
    u16* wqa_hi = (u16*)(wp);                  wp += (size_t)NQA * CDIM * 2;
    u16* wo_hi  = (u16*)(wp);                  wp += (size_t)CDIM * CDIM * 2;
    u16* wo_lo  = (u16*)(wp);                  wp += (size_t)CDIM * CDIM * 2;
    float* ws_off = (float*)(wp);              wp += (size_t)MROWS * NOFF * 4;
    float* ws_a   = (float*)(wp);
    u16* t_hi = val_hi;
    u16* t_lo = val_lo;

    const dim3 blk(256);
    const int n4_qv = MROWS * CDIM / 4;       // 688128

    // ---- splits (2 dispatches) ----
    split_vq_kernel<<<dim3(2 * n4_qv / 256), blk, 0, stream>>>(
        value, query, val_hi, val_lo, q_hi, n4_qv);
    split_w_kernel<<<dim3(200), blk, 0, stream>>>(
        Wv, Woff, Wa, Wo, wv_hi, wv_lo, wqa_hi, wo_hi, wo_lo);

    // ---- GEMMs + core ----
    // v = value @ Wv^T + bv  -> bf16 head-major (2-product)
    gemm_split_kernel<2, 1><<<dim3(MROWS / GBM, CDIM / GBN), blk, 0, stream>>>(
        val_hi, val_lo, wv_hi, wv_lo, bv, nullptr, v_bf16, nullptr,
        MROWS, CDIM, CDIM);
    // [off | a] = query @ [Woff;Wa]^T + [boff;ba] -> dual fp32 (pure bf16)
    gemm_split_kernel<1, 2><<<dim3(MROWS / GBM, (NQA + GBN - 1) / GBN), blk, 0, stream>>>(
        q_hi, nullptr, wqa_hi, nullptr, boff, ba, ws_off, ws_a,
        MROWS, NQA, CDIM);
    // sampling core -> t (bf16 hi/lo)
    msda_core_kernel<<<dim3(MROWS / 2), blk, 0, stream>>>(
        ws_off, ws_a, refp, v_bf16, t_hi, t_lo);
    // out = t @ Wo^T + bo -> fp32 (2-product)
    gemm_split_kernel<2, 0><<<dim3(MROWS / GBM, CDIM / GBN), blk, 0, stream>>>(
        t_hi, t_lo, wo_hi, wo_lo, bo, nullptr, out, nullptr,
        MROWS, CDIM, CDIM);
}

// Round 6
// 140.622 us; speedup vs baseline: 1.7432x; 1.0094x over previous
//
#include <hip/hip_runtime.h>
#include <hip/hip_bf16.h>
#include <cmath>

// Problem constants (from reference)
#define BATCH   2
#define NQ      5376
#define NV      5376
#define CDIM    256
#define HEADS   8
#define HD      32
#define LEVELS  3
#define POINTS  4
#define TP      96      // HEADS*LEVELS*POINTS
#define MROWS   (BATCH*NQ)   // 10752
#define NOFF    (TP*2)       // 192
#define NQA     (NOFF+TP)    // 288 merged off||a columns
#define N4_VQ   (MROWS*CDIM/4)   // 688128 float4 per (value|query)

typedef __attribute__((ext_vector_type(8))) short bf16x8;
typedef __attribute__((ext_vector_type(4))) float f32x4;
typedef unsigned short u16;
typedef unsigned int   u32;

#define AS1 __attribute__((address_space(1)))
#define AS3 __attribute__((address_space(3)))

__device__ __forceinline__ void g2lds16(const void* g, void* l) {
    // async global->LDS, 16B per lane; LDS dest = wave-uniform base + lane*16
    __builtin_amdgcn_global_load_lds((const AS1 void*)g, (AS3 void*)l, 16, 0, 0);
}

__device__ __forceinline__ u16 bf_of(float f) {
    union { __hip_bfloat16 h; u16 s; } u;
    u.h = __float2bfloat16(f);
    return u.s;
}
__device__ __forceinline__ float bf_back(u16 s) {
    return __uint_as_float((u32)s << 16);
}

// ---------------------------------------------------------------------------
// One fused split kernel: value -> hi+lo, query -> hi, Wv -> hi+lo,
// merged Woff||Wa -> hi, Wo -> hi+lo. Range-routed on flat float4 index.
// Grid = 5576 blocks x 256 exactly.
// ---------------------------------------------------------------------------
__global__ __launch_bounds__(256) void split_all_kernel(
    const float* __restrict__ value, const float* __restrict__ query,
    const float* __restrict__ Wv, const float* __restrict__ Woff,
    const float* __restrict__ Wa, const float* __restrict__ Wo,
    u16* __restrict__ vhi, u16* __restrict__ vlo, u16* __restrict__ qhi,
    u16* __restrict__ wv_hi, u16* __restrict__ wv_lo,
    u16* __restrict__ wqa_hi,
    u16* __restrict__ wo_hi, u16* __restrict__ wo_lo)
{
    const int i = blockIdx.x * 256 + threadIdx.x;
    int j; const float* src; u16 *dh, *dl;
    if (i < N4_VQ) {
        j = i; src = value + (size_t)j * 4; dh = vhi; dl = vlo;
    } else if (i < 2 * N4_VQ) {
        j = i - N4_VQ; src = query + (size_t)j * 4; dh = qhi; dl = nullptr;
    } else if (i < 2 * N4_VQ + 16384) {
        j = i - 2 * N4_VQ; src = Wv + (size_t)j * 4; dh = wv_hi; dl = wv_lo;
    } else if (i < 2 * N4_VQ + 34816) {
        j = i - 2 * N4_VQ - 16384;
        const int row = j >> 6, c4 = j & 63;
        src = (row < NOFF) ? (Woff + (size_t)row * CDIM + c4 * 4)
                           : (Wa + (size_t)(row - NOFF) * CDIM + c4 * 4);
        dh = wqa_hi; dl = nullptr;
    } else {
        j = i - 2 * N4_VQ - 34816; src = Wo + (size_t)j * 4; dh = wo_hi; dl = wo_lo;
    }
    const float4 v = *reinterpret_cast<const float4*>(src);
    ushort4 h;
    h.x = bf_of(v.x); h.y = bf_of(v.y); h.z = bf_of(v.z); h.w = bf_of(v.w);
    reinterpret_cast<ushort4*>(dh)[j] = h;
    if (dl) {
        ushort4 l;
        l.x = bf_of(v.x - bf_back(h.x));
        l.y = bf_of(v.y - bf_back(h.y));
        l.z = bf_of(v.z - bf_back(h.z));
        l.w = bf_of(v.w - bf_back(h.w));
        reinterpret_cast<ushort4*>(dl)[j] = l;
    }
}

// ---------------------------------------------------------------------------
// bf16 MFMA GEMM body: C = A @ W^T + bias.
// NPROD: 1 = AhBh; 2 = + AlBh. Tile 64x64x32, 256 threads = 4 waves (2x2 of
// 32x32). global_load_lds x16 staging. M % 64 == 0, K % 32 == 0, N guarded.
// MODE 0: fp32 out (ld=N).
// MODE 1: bf16 out in HEAD-MAJOR value layout (B, HEADS, NV, HD).
// MODE 2: dual fp32 out: n<192 -> C1 (ld 192, bias), else C2 (ld 96, bias2).
// ---------------------------------------------------------------------------
#define GBM 64
#define GBN 64
#define GBK 32

template <int NPROD, int MODE>
__device__ __forceinline__ void gemm_body(
    int m0, int n0,
    const u16* __restrict__ Ah, const u16* __restrict__ Al,
    const u16* __restrict__ Bh, const u16* __restrict__ Bl,
    const float* __restrict__ bias, const float* __restrict__ bias2,
    void* __restrict__ Cout, void* __restrict__ Cout2,
    int N, int K,
    u16* sAh, u16* sAl, u16* sBh, u16* sBl)
{
    const int tid  = threadIdx.x;
    const int lane = tid & 63;
    const int wave = tid >> 6;
    const int wr   = wave & 1;     // m offset 32*wr
    const int wc   = wave >> 1;    // n offset 32*wc
    const int qm   = lane & 15;
    const int quad = lane >> 4;

    f32x4 acc[2][2];
    #pragma unroll
    for (int i = 0; i < 2; ++i)
        #pragma unroll
        for (int j = 0; j < 2; ++j)
            acc[i][j] = (f32x4){0.f, 0.f, 0.f, 0.f};

    // staging: each wave stages one 16-row chunk of each staged buffer
    const int srow = (wave << 4) + (lane >> 2);   // tile row
    const int sk   = (lane & 3) * 8;              // bf16 k-offset
    const int brc  = min(n0 + srow, N - 1);       // clamp OOB B rows

    for (int k0 = 0; k0 < K; k0 += GBK) {
        const size_t ga = (size_t)(m0 + srow) * K + k0 + sk;
        const size_t gb = (size_t)brc * K + k0 + sk;
        g2lds16(Ah + ga, sAh + wave * 512);
        if (NPROD >= 2) g2lds16(Al + ga, sAl + wave * 512);
        g2lds16(Bh + gb, sBh + wave * 512);
        __syncthreads();

        bf16x8 fah[2], fal[2], fbh[2];
        #pragma unroll
        for (int x = 0; x < 2; ++x) {
            const int rm = wr * 32 + x * 16 + qm;
            const int rn = wc * 32 + x * 16 + qm;
            fah[x] = *reinterpret_cast<const bf16x8*>(&sAh[rm * GBK + quad * 8]);
            fbh[x] = *reinterpret_cast<const bf16x8*>(&sBh[rn * GBK + quad * 8]);
            if (NPROD >= 2)
                fal[x] = *reinterpret_cast<const bf16x8*>(&sAl[rm * GBK + quad * 8]);
        }
        #pragma unroll
        for (int mi = 0; mi < 2; ++mi)
            #pragma unroll
            for (int ni = 0; ni < 2; ++ni) {
                acc[mi][ni] = __builtin_amdgcn_mfma_f32_16x16x32_bf16(
                    fah[mi], fbh[ni], acc[mi][ni], 0, 0, 0);
                if (NPROD >= 2)
                    acc[mi][ni] = __builtin_amdgcn_mfma_f32_16x16x32_bf16(
                        fal[mi], fbh[ni], acc[mi][ni], 0, 0, 0);
            }
        __syncthreads();
    }

    // epilogue: C/D layout col = lane&15 (n), row = quad*4 + reg (m)
    #pragma unroll
    for (int mi = 0; mi < 2; ++mi) {
        #pragma unroll
        for (int ni = 0; ni < 2; ++ni) {
            const int n = n0 + wc * 32 + ni * 16 + qm;
            if (n >= N) continue;
            float bn;
            if (MODE == 2) bn = (n < NOFF) ? bias[n] : bias2[n - NOFF];
            else           bn = bias[n];
            #pragma unroll
            for (int r = 0; r < 4; ++r) {
                const int m = m0 + wr * 32 + mi * 16 + quad * 4 + r;
                const float val = acc[mi][ni][r] + bn;
                if (MODE == 0) {
                    reinterpret_cast<float*>(Cout)[(size_t)m * N + n] = val;
                } else if (MODE == 1) {
                    // head-major (B, HEADS, NV, HD)
                    const int b = m / NV, rr = m - b * NV;
                    const int h = n >> 5, c = n & 31;
                    reinterpret_cast<u16*>(Cout)[
                        (((size_t)b * HEADS + h) * NV + rr) * HD + c] = bf_of(val);
                } else {
                    if (n < NOFF)
                        reinterpret_cast<float*>(Cout)[(size_t)m * NOFF + n] = val;
                    else
                        reinterpret_cast<float*>(Cout2)[(size_t)m * TP + (n - NOFF)] = val;
                }
            }
        }
    }
}

// Merged v-GEMM + qa-GEMM dispatch. Flattened grid, n-tile fastest so
// consecutive blocks share the same A tile (L2/L3 reuse).
// blocks [0, 672): v path (168 m-tiles x 4 n-tiles), NPROD=2, MODE=1.
// blocks [672, 1512): qa path (168 x 5), NPROD=1, MODE=2.
#define VBLOCKS (168 * 4)
__global__ __launch_bounds__(256) void gemm_vqa_kernel(
    const u16* __restrict__ vAh, const u16* __restrict__ vAl,
    const u16* __restrict__ vBh, const float* __restrict__ vbias,
    u16* __restrict__ vOut,
    const u16* __restrict__ qAh, const u16* __restrict__ qBh,
    const float* __restrict__ qb1, const float* __restrict__ qb2,
    float* __restrict__ qOut1, float* __restrict__ qOut2)
{
    __shared__ u16 sAh[GBM * GBK];   // 4 KB each
    __shared__ u16 sAl[GBM * GBK];
    __shared__ u16 sBh[GBN * GBK];
    const int bid = blockIdx.x;
    if (bid < VBLOCKS) {
        const int nt = bid & 3, mt = bid >> 2;
        gemm_body<2, 1>(mt * GBM, nt * GBN, vAh, vAl, vBh, nullptr,
                        vbias, nullptr, vOut, nullptr, CDIM, CDIM,
                        sAh, sAl, sBh, nullptr);
    } else {
        const int b2 = bid - VBLOCKS;
        const int nt = b2 % 5, mt = b2 / 5;
        gemm_body<1, 2>(mt * GBM, nt * GBN, qAh, nullptr, qBh, nullptr,
                        qb1, qb2, qOut1, qOut2, NQA, CDIM,
                        sAh, sAl, sBh, nullptr);
    }
}

// out = t @ Wo^T + bo, fp32 out. Flattened grid, n-tile fastest.
__global__ __launch_bounds__(256) void gemm_out_kernel(
    const u16* __restrict__ Ah, const u16* __restrict__ Al,
    const u16* __restrict__ Bh, const float* __restrict__ bias,
    float* __restrict__ Cout)
{
    __shared__ u16 sAh[GBM * GBK];
    __shared__ u16 sAl[GBM * GBK];
    __shared__ u16 sBh[GBN * GBK];
    const int bid = blockIdx.x;
    const int nt = bid & 3, mt = bid >> 2;
    gemm_body<2, 0>(mt * GBM, nt * GBN, Ah, Al, Bh, nullptr,
                    bias, nullptr, Cout, nullptr, CDIM, CDIM,
                    sAh, sAl, sBh, nullptr);
}

// ---------------------------------------------------------------------------
// MSDA core v5 (unchanged from round 5): 2 queries/block, head-major bf16 v,
// dwordx2 gathers, 2 tap-replicas combined via shfl_xor(8).
// ---------------------------------------------------------------------------
__global__ __launch_bounds__(256) void msda_core_kernel(
    const float* __restrict__ off,   // (B*NQ, 192)
    const float* __restrict__ alog,  // (B*NQ, 96)
    const float* __restrict__ refp,  // (B*NQ, 2)
    const u16*   __restrict__ v,     // (B, HEADS, NV, HD) bf16
    u16* __restrict__ t_hi,          // (B*NQ, 256) bf16
    u16* __restrict__ t_lo)          // (B*NQ, 256) bf16
{
    const int tid  = threadIdx.x;
    const int half = tid >> 7;          // which of the 2 queries
    const int ht   = tid & 127;
    const int bq   = blockIdx.x * 2 + half;
    const int b    = bq / NQ;

    __shared__ float s_w[2][TP];
    __shared__ int   s_idx[2][TP][4];   // spatial*64 byte offsets in head plane
    __shared__ float s_twt[2][TP][4];

    if (ht < TP) s_w[half][ht] = alog[(size_t)bq * TP + ht];
    __syncthreads();

    if (ht < HEADS) {
        float mx = -1e30f;
        #pragma unroll
        for (int i = 0; i < 12; ++i) mx = fmaxf(mx, s_w[half][ht * 12 + i]);
        float e[12];
        float sum = 0.f;
        #pragma unroll
        for (int i = 0; i < 12; ++i) {
            e[i] = expf(s_w[half][ht * 12 + i] - mx);
            sum += e[i];
        }
        const float inv = 1.f / sum;
        #pragma unroll
        for (int i = 0; i < 12; ++i) s_w[half][ht * 12 + i] = e[i] * inv;
    }
    __syncthreads();

    if (ht < TP) {
        const int j  = ht;
        const int jj = j % 12;
        const int l  = jj >> 2;
        const int Wl    = (l == 0) ? 64 : (l == 1) ? 32 : 16;
        const int start = (l == 0) ? 0 : (l == 1) ? 4096 : 5120;

        const float refx = refp[(size_t)bq * 2 + 0];
        const float refy = refp[(size_t)bq * 2 + 1];
        const float lx = fminf(fmaxf(refx + off[(size_t)bq * NOFF + j * 2 + 0], 0.f), 1.f) * (float)Wl - 0.5f;
        const float ly = fminf(fmaxf(refy + off[(size_t)bq * NOFF + j * 2 + 1], 0.f), 1.f) * (float)Wl - 0.5f;
        const float fx0 = floorf(lx), fy0 = floorf(ly);
        const int   x0  = (int)fx0,   y0  = (int)fy0;
        const float wx1 = lx - fx0,   wy1 = ly - fy0;
        const float wx0 = 1.f - wx1,  wy0 = 1.f - wy1;
        const float aw  = s_w[half][j];

        #pragma unroll
        for (int k = 0; k < 4; ++k) {
            const int dx = k & 1, dy = k >> 1;
            const int xi = x0 + dx, yi = y0 + dy;
            const bool ok = (xi >= 0) & (xi < Wl) & (yi >= 0) & (yi < Wl);
            const int xc = min(max(xi, 0), Wl - 1);
            const int yc = min(max(yi, 0), Wl - 1);
            s_idx[half][j][k] = (start + yc * Wl + xc) * (HD * 2);  // 64 B rows
            const float wxy = (dx ? wx1 : wx0) * (dy ? wy1 : wy0);
            s_twt[half][j][k] = ok ? aw * wxy : 0.f;
        }
    }
    __syncthreads();

    const int h   = ht >> 4;     // 0..7
    const int sub = ht & 15;
    const int q   = sub & 7;     // channel quad: channels 4q..4q+3
    const int rep = sub >> 3;    // replica 0/1 -> taps [6r, 6r+6)
    const char* vb = (const char*)v + (((size_t)b * HEADS + h) * NV) * (HD * 2) + q * 8;

    float acc0 = 0.f, acc1 = 0.f, acc2 = 0.f, acc3 = 0.f;
    #pragma unroll
    for (int g = 0; g < 3; ++g) {        // 3 groups x 2 taps x 4 corners = 8 loads
        uint2 raw[8];
        float wt[8];
        #pragma unroll
        for (int pp = 0; pp < 2; ++pp) {
            const int j = h * 12 + rep * 6 + g * 2 + pp;
            const int4   ix = *reinterpret_cast<const int4*>(&s_idx[half][j][0]);
            const float4 tw = *reinterpret_cast<const float4*>(&s_twt[half][j][0]);
            raw[pp * 4 + 0] = *reinterpret_cast<const uint2*>(vb + ix.x);
            raw[pp * 4 + 1] = *reinterpret_cast<const uint2*>(vb + ix.y);
            raw[pp * 4 + 2] = *reinterpret_cast<const uint2*>(vb + ix.z);
            raw[pp * 4 + 3] = *reinterpret_cast<const uint2*>(vb + ix.w);
            wt[pp * 4 + 0] = tw.x; wt[pp * 4 + 1] = tw.y;
            wt[pp * 4 + 2] = tw.z; wt[pp * 4 + 3] = tw.w;
        }
        #pragma unroll
        for (int k = 0; k < 8; ++k) {
            acc0 += wt[k] * __uint_as_float(raw[k].x << 16);
            acc1 += wt[k] * __uint_as_float(raw[k].x & 0xffff0000u);
            acc2 += wt[k] * __uint_as_float(raw[k].y << 16);
            acc3 += wt[k] * __uint_as_float(raw[k].y & 0xffff0000u);
        }
    }

    // combine the two tap-replicas (lanes differ in bit 3)
    acc0 += __shfl_xor(acc0, 8);
    acc1 += __shfl_xor(acc1, 8);
    acc2 += __shfl_xor(acc2, 8);
    acc3 += __shfl_xor(acc3, 8);

    if (rep == 0) {
        ushort4 hh, ll;
        hh.x = bf_of(acc0); ll.x = bf_of(acc0 - bf_back(hh.x));
        hh.y = bf_of(acc1); ll.y = bf_of(acc1 - bf_back(hh.y));
        hh.z = bf_of(acc2); ll.z = bf_of(acc2 - bf_back(hh.z));
        hh.w = bf_of(acc3); ll.w = bf_of(acc3 - bf_back(hh.w));
        const size_t base = (size_t)bq * CDIM + h * HD + q * 4;
        *reinterpret_cast<ushort4*>(t_hi + base) = hh;
        *reinterpret_cast<ushort4*>(t_lo + base) = ll;
    }
}

// ---------------------------------------------------------------------------
// Launch: 4 dispatches total.
// ---------------------------------------------------------------------------
extern "C" void kernel_launch(void* const* d_in, const int* in_sizes, int n_in,
                              void* d_out, int out_size, void* d_ws, size_t ws_size,
                              hipStream_t stream)
{
    const float* query = (const float*)d_in[0];   // (B,NQ,C)
    const float* refp  = (const float*)d_in[1];   // (B,NQ,2)
    const float* value = (const float*)d_in[2];   // (B,NV,C)
    const float* Wv    = (const float*)d_in[3];   // (C,C)
    const float* bv    = (const float*)d_in[4];
    const float* Woff  = (const float*)d_in[5];   // (192,C)
    const float* boff  = (const float*)d_in[6];
    const float* Wa    = (const float*)d_in[7];   // (96,C)
    const float* ba    = (const float*)d_in[8];
    const float* Wo    = (const float*)d_in[9];   // (C,C)
    const float* bo    = (const float*)d_in[10];
    float* out = (float*)d_out;

    // ---- workspace layout ----
    char* w = (char*)d_ws;
    const size_t SZ_QV = (size_t)MROWS * CDIM * 2;   // 5.5 MB per bf16 matrix
    u16* q_hi   = (u16*)(w);
    u16* val_hi = (u16*)(w + 1 * SZ_QV);      // dead after v-GEMM -> reused as t
    u16* val_lo = (u16*)(w + 2 * SZ_QV);
    u16* v_bf16 = (u16*)(w + 3 * SZ_QV);      // gather source, head-major
    char* wp    = w + 4 * SZ_QV;
    u16* wv_hi  = (u16*)(wp);                  wp += (size_t)CDIM * CDIM * 2;
    u16* wv_lo  = (u16*)(wp);                  wp += (size_t)CDIM * CDIM * 2;
    u16* wqa_hi = (u16*)(wp);                  wp += (size_t)NQA * CDIM * 2;
    u16* wo_hi  = (u16*)(wp);                  wp += (size_t)CDIM * CDIM * 2;
    u16* wo_lo  = (u16*)(wp);                  wp += (size_t)CDIM * CDIM * 2;
    float* ws_off = (float*)(wp);              wp += (size_t)MROWS * NOFF * 4;
    float* ws_a   = (float*)(wp);
    u16* t_hi = val_hi;
    u16* t_lo = val_lo;

    const dim3 blk(256);

    // 1) all splits
    split_all_kernel<<<dim3((2 * N4_VQ + 51200) / 256), blk, 0, stream>>>(
        value, query, Wv, Woff, Wa, Wo,
        val_hi, val_lo, q_hi, wv_hi, wv_lo, wqa_hi, wo_hi, wo_lo);

    // 2) v-GEMM (bf16 head-major out) + qa-GEMM (dual fp32 out), one dispatch
    gemm_vqa_kernel<<<dim3(VBLOCKS + (MROWS / GBM) * 5), blk, 0, stream>>>(
        val_hi, val_lo, wv_hi, bv, v_bf16,
        q_hi, wqa_hi, boff, ba, ws_off, ws_a);

    // 3) sampling core -> t (bf16 hi/lo)
    msda_core_kernel<<<dim3(MROWS / 2), blk, 0, stream>>>(
        ws_off, ws_a, refp, v_bf16, t_hi, t_lo);

    // 4) out = t @ Wo^T + bo
    gemm_out_kernel<<<dim3((MROWS / GBM) * 4), blk, 0, stream>>>(
        t_hi, t_lo, wo_hi, bo, out);
}

// Round 7
// 138.919 us; speedup vs baseline: 1.7646x; 1.0123x over previous
//
#include <hip/hip_runtime.h>
#include <hip/hip_bf16.h>
#include <cmath>

// Problem constants (from reference)
#define BATCH   2
#define NQ      5376
#define NV      5376
#define CDIM    256
#define HEADS   8
#define HD      32
#define LEVELS  3
#define POINTS  4
#define TP      96      // HEADS*LEVELS*POINTS
#define MROWS   (BATCH*NQ)   // 10752
#define NOFF    (TP*2)       // 192
#define NQA     (NOFF+TP)    // 288 merged off||a columns

typedef __attribute__((ext_vector_type(8))) short bf16x8;
typedef __attribute__((ext_vector_type(4))) float f32x4;
typedef unsigned short u16;
typedef unsigned int   u32;

#define AS1 __attribute__((address_space(1)))
#define AS3 __attribute__((address_space(3)))

__device__ __forceinline__ void g2lds16(const void* g, void* l) {
    // async global->LDS, 16B per lane; LDS dest = wave-uniform base + lane*16
    __builtin_amdgcn_global_load_lds((const AS1 void*)g, (AS3 void*)l, 16, 0, 0);
}

__device__ __forceinline__ u16 bf_of(float f) {
    union { __hip_bfloat16 h; u16 s; } u;
    u.h = __float2bfloat16(f);
    return u.s;
}
__device__ __forceinline__ float bf_back(u16 s) {
    return __uint_as_float((u32)s << 16);
}

// convert float4 -> 4 bf16 (hi) packed, and optionally residual (lo)
__device__ __forceinline__ ushort4 cvt_hi(float4 v) {
    ushort4 h;
    h.x = bf_of(v.x); h.y = bf_of(v.y); h.z = bf_of(v.z); h.w = bf_of(v.w);
    return h;
}
__device__ __forceinline__ ushort4 cvt_lo(float4 v, ushort4 h) {
    ushort4 l;
    l.x = bf_of(v.x - bf_back(h.x));
    l.y = bf_of(v.y - bf_back(h.y));
    l.z = bf_of(v.z - bf_back(h.z));
    l.w = bf_of(v.w - bf_back(h.w));
    return l;
}

// ---------------------------------------------------------------------------
// GEMM tiles: 64x64x32, 256 threads = 4 waves (2x2 of 32x32 wave tiles).
// fp32 sources are converted to bf16 hi(/lo) during staging (fused split).
// ---------------------------------------------------------------------------
#define GBM 64
#define GBN 64
#define GBK 32

// MFMA compute + epilogue shared pieces are inlined per kernel to keep the
// staging paths specialized.

// --- kernel 1: v-GEMM (value @ Wv^T + bv -> bf16 head-major) and
//               qa-GEMM (query @ [Woff;Wa]^T + bias -> bf16 off||a), merged.
// Flattened grid, n-tile fastest. blocks [0,672): v path; [672,1512): qa.
#define VBLOCKS (168 * 4)
__global__ __launch_bounds__(256) void gemm_vqa_kernel(
    const float* __restrict__ value, const float* __restrict__ Wv,
    const float* __restrict__ bv, u16* __restrict__ vOut,
    const float* __restrict__ query, const float* __restrict__ Woff,
    const float* __restrict__ Wa,
    const float* __restrict__ boff, const float* __restrict__ ba,
    u16* __restrict__ offOut, u16* __restrict__ aOut)
{
    __shared__ u16 sAh[GBM * GBK];   // 4 KB each
    __shared__ u16 sAl[GBM * GBK];
    __shared__ u16 sBh[GBN * GBK];

    const int bid = blockIdx.x;
    const bool vpath = bid < VBLOCKS;
    int m0, n0;
    if (vpath) { m0 = (bid >> 2) * GBM;           n0 = (bid & 3) * GBN; }
    else       { const int b2 = bid - VBLOCKS;
                 m0 = (b2 / 5) * GBM;             n0 = (b2 % 5) * GBN; }

    const int tid  = threadIdx.x;
    const int lane = tid & 63;
    const int wave = tid >> 6;
    const int wr   = wave & 1;
    const int wc   = wave >> 1;
    const int qm   = lane & 15;
    const int quad = lane >> 4;

    // staging map: row = tid>>2 (0..63), k-offset = (tid&3)*8 floats
    const int srow = tid >> 2;
    const int sc   = (tid & 3) * 8;

    // A source row (fp32)
    const float* Asrc = (vpath ? value : query) + (size_t)(m0 + srow) * CDIM;
    // B source row (fp32), row-routed for the merged Woff||Wa path
    const float* Bsrc;
    if (vpath) {
        Bsrc = Wv + (size_t)(n0 + srow) * CDIM;
    } else {
        const int rg = min(n0 + srow, NQA - 1);
        Bsrc = (rg < NOFF) ? (Woff + (size_t)rg * CDIM)
                           : (Wa + (size_t)(rg - NOFF) * CDIM);
    }

    f32x4 acc[2][2];
    #pragma unroll
    for (int i = 0; i < 2; ++i)
        #pragma unroll
        for (int j = 0; j < 2; ++j)
            acc[i][j] = (f32x4){0.f, 0.f, 0.f, 0.f};

    for (int k0 = 0; k0 < CDIM; k0 += GBK) {
        // ---- stage A (hi, + lo on v path) ----
        const float4 a0 = *reinterpret_cast<const float4*>(&Asrc[k0 + sc]);
        const float4 a1 = *reinterpret_cast<const float4*>(&Asrc[k0 + sc + 4]);
        const ushort4 ah0 = cvt_hi(a0), ah1 = cvt_hi(a1);
        *reinterpret_cast<ushort4*>(&sAh[srow * GBK + sc])     = ah0;
        *reinterpret_cast<ushort4*>(&sAh[srow * GBK + sc + 4]) = ah1;
        if (vpath) {
            *reinterpret_cast<ushort4*>(&sAl[srow * GBK + sc])     = cvt_lo(a0, ah0);
            *reinterpret_cast<ushort4*>(&sAl[srow * GBK + sc + 4]) = cvt_lo(a1, ah1);
        }
        // ---- stage B (hi only) ----
        const float4 b0 = *reinterpret_cast<const float4*>(&Bsrc[k0 + sc]);
        const float4 b1 = *reinterpret_cast<const float4*>(&Bsrc[k0 + sc + 4]);
        *reinterpret_cast<ushort4*>(&sBh[srow * GBK + sc])     = cvt_hi(b0);
        *reinterpret_cast<ushort4*>(&sBh[srow * GBK + sc + 4]) = cvt_hi(b1);
        __syncthreads();

        bf16x8 fah[2], fal[2], fbh[2];
        #pragma unroll
        for (int x = 0; x < 2; ++x) {
            const int rm = wr * 32 + x * 16 + qm;
            const int rn = wc * 32 + x * 16 + qm;
            fah[x] = *reinterpret_cast<const bf16x8*>(&sAh[rm * GBK + quad * 8]);
            fbh[x] = *reinterpret_cast<const bf16x8*>(&sBh[rn * GBK + quad * 8]);
            if (vpath)
                fal[x] = *reinterpret_cast<const bf16x8*>(&sAl[rm * GBK + quad * 8]);
        }
        #pragma unroll
        for (int mi = 0; mi < 2; ++mi)
            #pragma unroll
            for (int ni = 0; ni < 2; ++ni) {
                acc[mi][ni] = __builtin_amdgcn_mfma_f32_16x16x32_bf16(
                    fah[mi], fbh[ni], acc[mi][ni], 0, 0, 0);
                if (vpath)
                    acc[mi][ni] = __builtin_amdgcn_mfma_f32_16x16x32_bf16(
                        fal[mi], fbh[ni], acc[mi][ni], 0, 0, 0);
            }
        __syncthreads();
    }

    // epilogue: C/D layout col = lane&15 (n), row = quad*4 + reg (m)
    #pragma unroll
    for (int mi = 0; mi < 2; ++mi) {
        #pragma unroll
        for (int ni = 0; ni < 2; ++ni) {
            const int n = n0 + wc * 32 + ni * 16 + qm;
            if (vpath) {
                const float bn = bv[n];
                #pragma unroll
                for (int r = 0; r < 4; ++r) {
                    const int m = m0 + wr * 32 + mi * 16 + quad * 4 + r;
                    const float val = acc[mi][ni][r] + bn;
                    // head-major (B, HEADS, NV, HD)
                    const int b = m / NV, rr = m - b * NV;
                    const int h = n >> 5, c = n & 31;
                    vOut[(((size_t)b * HEADS + h) * NV + rr) * HD + c] = bf_of(val);
                }
            } else {
                if (n >= NQA) continue;
                const float bn = (n < NOFF) ? boff[n] : ba[n - NOFF];
                #pragma unroll
                for (int r = 0; r < 4; ++r) {
                    const int m = m0 + wr * 32 + mi * 16 + quad * 4 + r;
                    const float val = acc[mi][ni][r] + bn;
                    if (n < NOFF)
                        offOut[(size_t)m * NOFF + n] = bf_of(val);
                    else
                        aOut[(size_t)m * TP + (n - NOFF)] = bf_of(val);
                }
            }
        }
    }
}

// --- kernel 3: out = t @ Wo^T + bo (fp32 out). A = t hi/lo bf16 (g2lds
// staging), B = Wo fp32 converted during staging. Flattened, n-fastest.
__global__ __launch_bounds__(256) void gemm_out_kernel(
    const u16* __restrict__ Ah, const u16* __restrict__ Al,
    const float* __restrict__ Wo, const float* __restrict__ bias,
    float* __restrict__ Cout)
{
    __shared__ u16 sAh[GBM * GBK];
    __shared__ u16 sAl[GBM * GBK];
    __shared__ u16 sBh[GBN * GBK];

    const int bid = blockIdx.x;
    const int m0 = (bid >> 2) * GBM;
    const int n0 = (bid & 3) * GBN;

    const int tid  = threadIdx.x;
    const int lane = tid & 63;
    const int wave = tid >> 6;
    const int wr   = wave & 1;
    const int wc   = wave >> 1;
    const int qm   = lane & 15;
    const int quad = lane >> 4;

    // g2lds map for A (bf16): row = (wave<<4)+(lane>>2), k = (lane&3)*8
    const int arow = (wave << 4) + (lane >> 2);
    const int ak   = (lane & 3) * 8;
    // VALU map for B (fp32)
    const int srow = tid >> 2;
    const int sc   = (tid & 3) * 8;
    const float* Bsrc = Wo + (size_t)(n0 + srow) * CDIM;

    f32x4 acc[2][2];
    #pragma unroll
    for (int i = 0; i < 2; ++i)
        #pragma unroll
        for (int j = 0; j < 2; ++j)
            acc[i][j] = (f32x4){0.f, 0.f, 0.f, 0.f};

    for (int k0 = 0; k0 < CDIM; k0 += GBK) {
        const size_t ga = (size_t)(m0 + arow) * CDIM + k0 + ak;
        g2lds16(Ah + ga, sAh + wave * 512);
        g2lds16(Al + ga, sAl + wave * 512);
        const float4 b0 = *reinterpret_cast<const float4*>(&Bsrc[k0 + sc]);
        const float4 b1 = *reinterpret_cast<const float4*>(&Bsrc[k0 + sc + 4]);
        *reinterpret_cast<ushort4*>(&sBh[srow * GBK + sc])     = cvt_hi(b0);
        *reinterpret_cast<ushort4*>(&sBh[srow * GBK + sc + 4]) = cvt_hi(b1);
        __syncthreads();

        bf16x8 fah[2], fal[2], fbh[2];
        #pragma unroll
        for (int x = 0; x < 2; ++x) {
            const int rm = wr * 32 + x * 16 + qm;
            const int rn = wc * 32 + x * 16 + qm;
            fah[x] = *reinterpret_cast<const bf16x8*>(&sAh[rm * GBK + quad * 8]);
            fal[x] = *reinterpret_cast<const bf16x8*>(&sAl[rm * GBK + quad * 8]);
            fbh[x] = *reinterpret_cast<const bf16x8*>(&sBh[rn * GBK + quad * 8]);
        }
        #pragma unroll
        for (int mi = 0; mi < 2; ++mi)
            #pragma unroll
            for (int ni = 0; ni < 2; ++ni) {
                acc[mi][ni] = __builtin_amdgcn_mfma_f32_16x16x32_bf16(
                    fah[mi], fbh[ni], acc[mi][ni], 0, 0, 0);
                acc[mi][ni] = __builtin_amdgcn_mfma_f32_16x16x32_bf16(
                    fal[mi], fbh[ni], acc[mi][ni], 0, 0, 0);
            }
        __syncthreads();
    }

    #pragma unroll
    for (int mi = 0; mi < 2; ++mi) {
        #pragma unroll
        for (int ni = 0; ni < 2; ++ni) {
            const int n = n0 + wc * 32 + ni * 16 + qm;
            const float bn = bias[n];
            #pragma unroll
            for (int r = 0; r < 4; ++r) {
                const int m = m0 + wr * 32 + mi * 16 + quad * 4 + r;
                Cout[(size_t)m * CDIM + n] = acc[mi][ni][r] + bn;
            }
        }
    }
}

// ---------------------------------------------------------------------------
// MSDA core (v5 body, off/alog now bf16): 2 queries/block, head-major bf16 v,
// dwordx2 gathers, 2 tap-replicas combined via shfl_xor(8).
// ---------------------------------------------------------------------------
__global__ __launch_bounds__(256) void msda_core_kernel(
    const u16* __restrict__ off,    // (B*NQ, 192) bf16
    const u16* __restrict__ alog,   // (B*NQ, 96) bf16
    const float* __restrict__ refp, // (B*NQ, 2)
    const u16*   __restrict__ v,    // (B, HEADS, NV, HD) bf16
    u16* __restrict__ t_hi,         // (B*NQ, 256) bf16
    u16* __restrict__ t_lo)         // (B*NQ, 256) bf16
{
    const int tid  = threadIdx.x;
    const int half = tid >> 7;          // which of the 2 queries
    const int ht   = tid & 127;
    const int bq   = blockIdx.x * 2 + half;
    const int b    = bq / NQ;

    __shared__ float s_w[2][TP];
    __shared__ int   s_idx[2][TP][4];   // spatial*64 byte offsets in head plane
    __shared__ float s_twt[2][TP][4];

    if (ht < TP) s_w[half][ht] = bf_back(alog[(size_t)bq * TP + ht]);
    __syncthreads();

    if (ht < HEADS) {
        float mx = -1e30f;
        #pragma unroll
        for (int i = 0; i < 12; ++i) mx = fmaxf(mx, s_w[half][ht * 12 + i]);
        float e[12];
        float sum = 0.f;
        #pragma unroll
        for (int i = 0; i < 12; ++i) {
            e[i] = expf(s_w[half][ht * 12 + i] - mx);
            sum += e[i];
        }
        const float inv = 1.f / sum;
        #pragma unroll
        for (int i = 0; i < 12; ++i) s_w[half][ht * 12 + i] = e[i] * inv;
    }
    __syncthreads();

    if (ht < TP) {
        const int j  = ht;
        const int jj = j % 12;
        const int l  = jj >> 2;
        const int Wl    = (l == 0) ? 64 : (l == 1) ? 32 : 16;
        const int start = (l == 0) ? 0 : (l == 1) ? 4096 : 5120;

        const float refx = refp[(size_t)bq * 2 + 0];
        const float refy = refp[(size_t)bq * 2 + 1];
        const float ox = bf_back(off[(size_t)bq * NOFF + j * 2 + 0]);
        const float oy = bf_back(off[(size_t)bq * NOFF + j * 2 + 1]);
        const float lx = fminf(fmaxf(refx + ox, 0.f), 1.f) * (float)Wl - 0.5f;
        const float ly = fminf(fmaxf(refy + oy, 0.f), 1.f) * (float)Wl - 0.5f;
        const float fx0 = floorf(lx), fy0 = floorf(ly);
        const int   x0  = (int)fx0,   y0  = (int)fy0;
        const float wx1 = lx - fx0,   wy1 = ly - fy0;
        const float wx0 = 1.f - wx1,  wy0 = 1.f - wy1;
        const float aw  = s_w[half][j];

        #pragma unroll
        for (int k = 0; k < 4; ++k) {
            const int dx = k & 1, dy = k >> 1;
            const int xi = x0 + dx, yi = y0 + dy;
            const bool ok = (xi >= 0) & (xi < Wl) & (yi >= 0) & (yi < Wl);
            const int xc = min(max(xi, 0), Wl - 1);
            const int yc = min(max(yi, 0), Wl - 1);
            s_idx[half][j][k] = (start + yc * Wl + xc) * (HD * 2);  // 64 B rows
            const float wxy = (dx ? wx1 : wx0) * (dy ? wy1 : wy0);
            s_twt[half][j][k] = ok ? aw * wxy : 0.f;
        }
    }
    __syncthreads();

    const int h   = ht >> 4;     // 0..7
    const int sub = ht & 15;
    const int q   = sub & 7;     // channel quad: channels 4q..4q+3
    const int rep = sub >> 3;    // replica 0/1 -> taps [6r, 6r+6)
    const char* vb = (const char*)v + (((size_t)b * HEADS + h) * NV) * (HD * 2) + q * 8;

    float acc0 = 0.f, acc1 = 0.f, acc2 = 0.f, acc3 = 0.f;
    #pragma unroll
    for (int g = 0; g < 3; ++g) {        // 3 groups x 2 taps x 4 corners = 8 loads
        uint2 raw[8];
        float wt[8];
        #pragma unroll
        for (int pp = 0; pp < 2; ++pp) {
            const int j = h * 12 + rep * 6 + g * 2 + pp;
            const int4   ix = *reinterpret_cast<const int4*>(&s_idx[half][j][0]);
            const float4 tw = *reinterpret_cast<const float4*>(&s_twt[half][j][0]);
            raw[pp * 4 + 0] = *reinterpret_cast<const uint2*>(vb + ix.x);
            raw[pp * 4 + 1] = *reinterpret_cast<const uint2*>(vb + ix.y);
            raw[pp * 4 + 2] = *reinterpret_cast<const uint2*>(vb + ix.z);
            raw[pp * 4 + 3] = *reinterpret_cast<const uint2*>(vb + ix.w);
            wt[pp * 4 + 0] = tw.x; wt[pp * 4 + 1] = tw.y;
            wt[pp * 4 + 2] = tw.z; wt[pp * 4 + 3] = tw.w;
        }
        #pragma unroll
        for (int k = 0; k < 8; ++k) {
            acc0 += wt[k] * __uint_as_float(raw[k].x << 16);
            acc1 += wt[k] * __uint_as_float(raw[k].x & 0xffff0000u);
            acc2 += wt[k] * __uint_as_float(raw[k].y << 16);
            acc3 += wt[k] * __uint_as_float(raw[k].y & 0xffff0000u);
        }
    }

    // combine the two tap-replicas (lanes differ in bit 3)
    acc0 += __shfl_xor(acc0, 8);
    acc1 += __shfl_xor(acc1, 8);
    acc2 += __shfl_xor(acc2, 8);
    acc3 += __shfl_xor(acc3, 8);

    if (rep == 0) {
        ushort4 hh, ll;
        hh.x = bf_of(acc0); ll.x = bf_of(acc0 - bf_back(hh.x));
        hh.y = bf_of(acc1); ll.y = bf_of(acc1 - bf_back(hh.y));
        hh.z = bf_of(acc2); ll.z = bf_of(acc2 - bf_back(hh.z));
        hh.w = bf_of(acc3); ll.w = bf_of(acc3 - bf_back(hh.w));
        const size_t base = (size_t)bq * CDIM + h * HD + q * 4;
        *reinterpret_cast<ushort4*>(t_hi + base) = hh;
        *reinterpret_cast<ushort4*>(t_lo + base) = ll;
    }
}

// ---------------------------------------------------------------------------
// Launch: 3 dispatches total (splits fused into GEMM staging).
// ---------------------------------------------------------------------------
extern "C" void kernel_launch(void* const* d_in, const int* in_sizes, int n_in,
                              void* d_out, int out_size, void* d_ws, size_t ws_size,
                              hipStream_t stream)
{
    const float* query = (const float*)d_in[0];   // (B,NQ,C)
    const float* refp  = (const float*)d_in[1];   // (B,NQ,2)
    const float* value = (const float*)d_in[2];   // (B,NV,C)
    const float* Wv    = (const float*)d_in[3];   // (C,C)
    const float* bv    = (const float*)d_in[4];
    const float* Woff  = (const float*)d_in[5];   // (192,C)
    const float* boff  = (const float*)d_in[6];
    const float* Wa    = (const float*)d_in[7];   // (96,C)
    const float* ba    = (const float*)d_in[8];
    const float* Wo    = (const float*)d_in[9];   // (C,C)
    const float* bo    = (const float*)d_in[10];
    float* out = (float*)d_out;

    // ---- workspace layout (all bf16) ----
    char* w = (char*)d_ws;
    const size_t SZ_T = (size_t)MROWS * CDIM * 2;     // 5.5 MB
    u16* v_bf16 = (u16*)(w);                          // head-major gather source
    u16* t_hi   = (u16*)(w + 1 * SZ_T);
    u16* t_lo   = (u16*)(w + 2 * SZ_T);
    u16* ws_off = (u16*)(w + 3 * SZ_T);               // (MROWS,192) bf16
    u16* ws_a   = (u16*)(w + 3 * SZ_T + (size_t)MROWS * NOFF * 2);

    const dim3 blk(256);

    // 1) v-GEMM (bf16 head-major out) + qa-GEMM (bf16 off||a out), fp32 in
    gemm_vqa_kernel<<<dim3(VBLOCKS + (MROWS / GBM) * 5), blk, 0, stream>>>(
        value, Wv, bv, v_bf16,
        query, Woff, Wa, boff, ba, ws_off, ws_a);

    // 2) sampling core -> t (bf16 hi/lo)
    msda_core_kernel<<<dim3(MROWS / 2), blk, 0, stream>>>(
        ws_off, ws_a, refp, v_bf16, t_hi, t_lo);

    // 3) out = t @ Wo^T + bo (fp32 out)
    gemm_out_kernel<<<dim3((MROWS / GBM) * 4), blk, 0, stream>>>(
        t_hi, t_lo, Wo, bo, out);
}

// Round 8
// 135.557 us; speedup vs baseline: 1.8083x; 1.0248x over previous
//
#include <hip/hip_runtime.h>
#include <hip/hip_bf16.h>
#include <cmath>

// Problem constants (from reference)
#define BATCH   2
#define NQ      5376
#define NV      5376
#define CDIM    256
#define HEADS   8
#define HD      32
#define LEVELS  3
#define POINTS  4
#define TP      96      // HEADS*LEVELS*POINTS
#define MROWS   (BATCH*NQ)   // 10752
#define NOFF    (TP*2)       // 192
#define NQA     (NOFF+TP)    // 288 merged off||a columns

typedef __attribute__((ext_vector_type(8))) short bf16x8;
typedef __attribute__((ext_vector_type(4))) float f32x4;
typedef unsigned short u16;
typedef unsigned int   u32;

#define AS1 __attribute__((address_space(1)))
#define AS3 __attribute__((address_space(3)))

__device__ __forceinline__ void g2lds16(const void* g, void* l) {
    // async global->LDS, 16B per lane; LDS dest = wave-uniform base + lane*16
    __builtin_amdgcn_global_load_lds((const AS1 void*)g, (AS3 void*)l, 16, 0, 0);
}

__device__ __forceinline__ u16 bf_of(float f) {
    union { __hip_bfloat16 h; u16 s; } u;
    u.h = __float2bfloat16(f);
    return u.s;
}
__device__ __forceinline__ float bf_back(u16 s) {
    return __uint_as_float((u32)s << 16);
}

// convert float4 -> 4 bf16 (hi) packed, and optionally residual (lo)
__device__ __forceinline__ ushort4 cvt_hi(float4 v) {
    ushort4 h;
    h.x = bf_of(v.x); h.y = bf_of(v.y); h.z = bf_of(v.z); h.w = bf_of(v.w);
    return h;
}
__device__ __forceinline__ ushort4 cvt_lo(float4 v, ushort4 h) {
    ushort4 l;
    l.x = bf_of(v.x - bf_back(h.x));
    l.y = bf_of(v.y - bf_back(h.y));
    l.z = bf_of(v.z - bf_back(h.z));
    l.w = bf_of(v.w - bf_back(h.w));
    return l;
}

// ---------------------------------------------------------------------------
// GEMM tiles: 64x64x32, 256 threads = 4 waves (2x2 of 32x32 wave tiles).
// fp32 sources are converted to bf16 hi(/lo) during staging (fused split).
// ---------------------------------------------------------------------------
#define GBM 64
#define GBN 64
#define GBK 32

// --- kernel 1: v-GEMM (value @ Wv^T + bv -> bf16 head-major) and
//               qa-GEMM (query @ [Woff;Wa]^T + bias -> bf16 off||a), merged.
// Flattened grid, n-tile fastest. blocks [0,672): v path; [672,1512): qa.
#define VBLOCKS (168 * 4)
__global__ __launch_bounds__(256) void gemm_vqa_kernel(
    const float* __restrict__ value, const float* __restrict__ Wv,
    const float* __restrict__ bv, u16* __restrict__ vOut,
    const float* __restrict__ query, const float* __restrict__ Woff,
    const float* __restrict__ Wa,
    const float* __restrict__ boff, const float* __restrict__ ba,
    u16* __restrict__ offOut, u16* __restrict__ aOut)
{
    __shared__ u16 sAh[GBM * GBK];   // 4 KB each
    __shared__ u16 sAl[GBM * GBK];
    __shared__ u16 sBh[GBN * GBK];

    const int bid = blockIdx.x;
    const bool vpath = bid < VBLOCKS;
    int m0, n0;
    if (vpath) { m0 = (bid >> 2) * GBM;           n0 = (bid & 3) * GBN; }
    else       { const int b2 = bid - VBLOCKS;
                 m0 = (b2 / 5) * GBM;             n0 = (b2 % 5) * GBN; }

    const int tid  = threadIdx.x;
    const int lane = tid & 63;
    const int wave = tid >> 6;
    const int wr   = wave & 1;
    const int wc   = wave >> 1;
    const int qm   = lane & 15;
    const int quad = lane >> 4;

    // staging map: row = tid>>2 (0..63), k-offset = (tid&3)*8 floats
    const int srow = tid >> 2;
    const int sc   = (tid & 3) * 8;

    // A source row (fp32)
    const float* Asrc = (vpath ? value : query) + (size_t)(m0 + srow) * CDIM;
    // B source row (fp32), row-routed for the merged Woff||Wa path
    const float* Bsrc;
    if (vpath) {
        Bsrc = Wv + (size_t)(n0 + srow) * CDIM;
    } else {
        const int rg = min(n0 + srow, NQA - 1);
        Bsrc = (rg < NOFF) ? (Woff + (size_t)rg * CDIM)
                           : (Wa + (size_t)(rg - NOFF) * CDIM);
    }

    f32x4 acc[2][2];
    #pragma unroll
    for (int i = 0; i < 2; ++i)
        #pragma unroll
        for (int j = 0; j < 2; ++j)
            acc[i][j] = (f32x4){0.f, 0.f, 0.f, 0.f};

    for (int k0 = 0; k0 < CDIM; k0 += GBK) {
        // ---- stage A (hi, + lo on v path) ----
        const float4 a0 = *reinterpret_cast<const float4*>(&Asrc[k0 + sc]);
        const float4 a1 = *reinterpret_cast<const float4*>(&Asrc[k0 + sc + 4]);
        const ushort4 ah0 = cvt_hi(a0), ah1 = cvt_hi(a1);
        *reinterpret_cast<ushort4*>(&sAh[srow * GBK + sc])     = ah0;
        *reinterpret_cast<ushort4*>(&sAh[srow * GBK + sc + 4]) = ah1;
        if (vpath) {
            *reinterpret_cast<ushort4*>(&sAl[srow * GBK + sc])     = cvt_lo(a0, ah0);
            *reinterpret_cast<ushort4*>(&sAl[srow * GBK + sc + 4]) = cvt_lo(a1, ah1);
        }
        // ---- stage B (hi only) ----
        const float4 b0 = *reinterpret_cast<const float4*>(&Bsrc[k0 + sc]);
        const float4 b1 = *reinterpret_cast<const float4*>(&Bsrc[k0 + sc + 4]);
        *reinterpret_cast<ushort4*>(&sBh[srow * GBK + sc])     = cvt_hi(b0);
        *reinterpret_cast<ushort4*>(&sBh[srow * GBK + sc + 4]) = cvt_hi(b1);
        __syncthreads();

        bf16x8 fah[2], fal[2], fbh[2];
        #pragma unroll
        for (int x = 0; x < 2; ++x) {
            const int rm = wr * 32 + x * 16 + qm;
            const int rn = wc * 32 + x * 16 + qm;
            fah[x] = *reinterpret_cast<const bf16x8*>(&sAh[rm * GBK + quad * 8]);
            fbh[x] = *reinterpret_cast<const bf16x8*>(&sBh[rn * GBK + quad * 8]);
            if (vpath)
                fal[x] = *reinterpret_cast<const bf16x8*>(&sAl[rm * GBK + quad * 8]);
        }
        #pragma unroll
        for (int mi = 0; mi < 2; ++mi)
            #pragma unroll
            for (int ni = 0; ni < 2; ++ni) {
                acc[mi][ni] = __builtin_amdgcn_mfma_f32_16x16x32_bf16(
                    fah[mi], fbh[ni], acc[mi][ni], 0, 0, 0);
                if (vpath)
                    acc[mi][ni] = __builtin_amdgcn_mfma_f32_16x16x32_bf16(
                        fal[mi], fbh[ni], acc[mi][ni], 0, 0, 0);
            }
        __syncthreads();
    }

    // epilogue: C/D layout col = lane&15 (n), row = quad*4 + reg (m)
    #pragma unroll
    for (int mi = 0; mi < 2; ++mi) {
        #pragma unroll
        for (int ni = 0; ni < 2; ++ni) {
            const int n = n0 + wc * 32 + ni * 16 + qm;
            if (vpath) {
                const float bn = bv[n];
                #pragma unroll
                for (int r = 0; r < 4; ++r) {
                    const int m = m0 + wr * 32 + mi * 16 + quad * 4 + r;
                    const float val = acc[mi][ni][r] + bn;
                    // head-major (B, HEADS, NV, HD)
                    const int b = m / NV, rr = m - b * NV;
                    const int h = n >> 5, c = n & 31;
                    vOut[(((size_t)b * HEADS + h) * NV + rr) * HD + c] = bf_of(val);
                }
            } else {
                if (n >= NQA) continue;
                const float bn = (n < NOFF) ? boff[n] : ba[n - NOFF];
                #pragma unroll
                for (int r = 0; r < 4; ++r) {
                    const int m = m0 + wr * 32 + mi * 16 + quad * 4 + r;
                    const float val = acc[mi][ni][r] + bn;
                    if (n < NOFF)
                        offOut[(size_t)m * NOFF + n] = bf_of(val);
                    else
                        aOut[(size_t)m * TP + (n - NOFF)] = bf_of(val);
                }
            }
        }
    }
}

// --- kernel 3: out = t @ Wo^T + bo (fp32 out). A = t_hi bf16 (g2lds staging,
// single product), B = Wo fp32 converted during staging. Flattened, n-fastest.
__global__ __launch_bounds__(256) void gemm_out_kernel(
    const u16* __restrict__ Ah,
    const float* __restrict__ Wo, const float* __restrict__ bias,
    float* __restrict__ Cout)
{
    __shared__ u16 sAh[GBM * GBK];
    __shared__ u16 sBh[GBN * GBK];

    const int bid = blockIdx.x;
    const int m0 = (bid >> 2) * GBM;
    const int n0 = (bid & 3) * GBN;

    const int tid  = threadIdx.x;
    const int lane = tid & 63;
    const int wave = tid >> 6;
    const int wr   = wave & 1;
    const int wc   = wave >> 1;
    const int qm   = lane & 15;
    const int quad = lane >> 4;

    // g2lds map for A (bf16): row = (wave<<4)+(lane>>2), k = (lane&3)*8
    const int arow = (wave << 4) + (lane >> 2);
    const int ak   = (lane & 3) * 8;
    // VALU map for B (fp32)
    const int srow = tid >> 2;
    const int sc   = (tid & 3) * 8;
    const float* Bsrc = Wo + (size_t)(n0 + srow) * CDIM;

    f32x4 acc[2][2];
    #pragma unroll
    for (int i = 0; i < 2; ++i)
        #pragma unroll
        for (int j = 0; j < 2; ++j)
            acc[i][j] = (f32x4){0.f, 0.f, 0.f, 0.f};

    for (int k0 = 0; k0 < CDIM; k0 += GBK) {
        const size_t ga = (size_t)(m0 + arow) * CDIM + k0 + ak;
        g2lds16(Ah + ga, sAh + wave * 512);
        const float4 b0 = *reinterpret_cast<const float4*>(&Bsrc[k0 + sc]);
        const float4 b1 = *reinterpret_cast<const float4*>(&Bsrc[k0 + sc + 4]);
        *reinterpret_cast<ushort4*>(&sBh[srow * GBK + sc])     = cvt_hi(b0);
        *reinterpret_cast<ushort4*>(&sBh[srow * GBK + sc + 4]) = cvt_hi(b1);
        __syncthreads();

        bf16x8 fah[2], fbh[2];
        #pragma unroll
        for (int x = 0; x < 2; ++x) {
            const int rm = wr * 32 + x * 16 + qm;
            const int rn = wc * 32 + x * 16 + qm;
            fah[x] = *reinterpret_cast<const bf16x8*>(&sAh[rm * GBK + quad * 8]);
            fbh[x] = *reinterpret_cast<const bf16x8*>(&sBh[rn * GBK + quad * 8]);
        }
        #pragma unroll
        for (int mi = 0; mi < 2; ++mi)
            #pragma unroll
            for (int ni = 0; ni < 2; ++ni)
                acc[mi][ni] = __builtin_amdgcn_mfma_f32_16x16x32_bf16(
                    fah[mi], fbh[ni], acc[mi][ni], 0, 0, 0);
        __syncthreads();
    }

    #pragma unroll
    for (int mi = 0; mi < 2; ++mi) {
        #pragma unroll
        for (int ni = 0; ni < 2; ++ni) {
            const int n = n0 + wc * 32 + ni * 16 + qm;
            const float bn = bias[n];
            #pragma unroll
            for (int r = 0; r < 4; ++r) {
                const int m = m0 + wr * 32 + mi * 16 + quad * 4 + r;
                Cout[(size_t)m * CDIM + n] = acc[mi][ni][r] + bn;
            }
        }
    }
}

// ---------------------------------------------------------------------------
// MSDA core v6: 4 queries/block (256 threads), 64 threads per query =
// 8 heads x 4 channel-octets x 2 tap-replicas. Gathers are dwordx4 (16 B):
// each 64 B corner row covered by exactly 4 lanes. Replicas combined via
// shfl_xor(4). Output t_hi only (bf16).
// ---------------------------------------------------------------------------
__global__ __launch_bounds__(256) void msda_core_kernel(
    const u16* __restrict__ off,    // (B*NQ, 192) bf16
    const u16* __restrict__ alog,   // (B*NQ, 96) bf16
    const float* __restrict__ refp, // (B*NQ, 2)
    const u16*   __restrict__ v,    // (B, HEADS, NV, HD) bf16
    u16* __restrict__ t_hi)         // (B*NQ, 256) bf16
{
    const int tid = threadIdx.x;
    const int bq0 = blockIdx.x * 4;

    __shared__ float s_w[4][TP];
    __shared__ int   s_idx[4][TP][4];   // spatial*64 byte offsets in head plane
    __shared__ float s_twt[4][TP][4];

    // logits for 4 queries (384 values)
    #pragma unroll
    for (int base = 0; base < 4 * TP; base += 256) {
        const int idx = base + tid;
        if (idx < 4 * TP) {
            const int q = idx / TP, j = idx - q * TP;
            s_w[q][j] = bf_back(alog[(size_t)(bq0 + q) * TP + j]);
        }
    }
    __syncthreads();

    // 32 softmaxes (4 queries x 8 heads)
    if (tid < 32) {
        const int q = tid >> 3, h = tid & 7;
        float mx = -1e30f;
        #pragma unroll
        for (int i = 0; i < 12; ++i) mx = fmaxf(mx, s_w[q][h * 12 + i]);
        float e[12];
        float sum = 0.f;
        #pragma unroll
        for (int i = 0; i < 12; ++i) {
            e[i] = expf(s_w[q][h * 12 + i] - mx);
            sum += e[i];
        }
        const float inv = 1.f / sum;
        #pragma unroll
        for (int i = 0; i < 12; ++i) s_w[q][h * 12 + i] = e[i] * inv;
    }
    __syncthreads();

    // taps for 4 queries (384 taps)
    #pragma unroll
    for (int base = 0; base < 4 * TP; base += 256) {
        const int idx = base + tid;
        if (idx < 4 * TP) {
            const int q = idx / TP, j = idx - q * TP;
            const int bq = bq0 + q;
            const int jj = j % 12;
            const int l  = jj >> 2;
            const int Wl    = (l == 0) ? 64 : (l == 1) ? 32 : 16;
            const int start = (l == 0) ? 0 : (l == 1) ? 4096 : 5120;

            const float refx = refp[(size_t)bq * 2 + 0];
            const float refy = refp[(size_t)bq * 2 + 1];
            const float ox = bf_back(off[(size_t)bq * NOFF + j * 2 + 0]);
            const float oy = bf_back(off[(size_t)bq * NOFF + j * 2 + 1]);
            const float lx = fminf(fmaxf(refx + ox, 0.f), 1.f) * (float)Wl - 0.5f;
            const float ly = fminf(fmaxf(refy + oy, 0.f), 1.f) * (float)Wl - 0.5f;
            const float fx0 = floorf(lx), fy0 = floorf(ly);
            const int   x0  = (int)fx0,   y0  = (int)fy0;
            const float wx1 = lx - fx0,   wy1 = ly - fy0;
            const float wx0 = 1.f - wx1,  wy0 = 1.f - wy1;
            const float aw  = s_w[q][j];

            #pragma unroll
            for (int k = 0; k < 4; ++k) {
                const int dx = k & 1, dy = k >> 1;
                const int xi = x0 + dx, yi = y0 + dy;
                const bool ok = (xi >= 0) & (xi < Wl) & (yi >= 0) & (yi < Wl);
                const int xc = min(max(xi, 0), Wl - 1);
                const int yc = min(max(yi, 0), Wl - 1);
                s_idx[q][j][k] = (start + yc * Wl + xc) * (HD * 2);  // 64 B rows
                const float wxy = (dx ? wx1 : wx0) * (dy ? wy1 : wy0);
                s_twt[q][j][k] = ok ? aw * wxy : 0.f;
            }
        }
    }
    __syncthreads();

    // gather: 64 threads per query
    const int qsel = tid >> 6;          // 0..3 (one wave per query)
    const int ht   = tid & 63;
    const int h    = ht >> 3;           // 0..7
    const int sub  = ht & 7;
    const int oct  = sub & 3;           // channels 8*oct .. 8*oct+7
    const int rep  = sub >> 2;          // replica 0/1 -> taps [6r, 6r+6)
    const int bq   = bq0 + qsel;
    const int b    = bq / NQ;
    const char* vb = (const char*)v + (((size_t)b * HEADS + h) * NV) * (HD * 2) + oct * 16;

    float acc[8] = {};
    #pragma unroll
    for (int g = 0; g < 3; ++g) {        // 3 groups x 2 taps x 4 corners = 8 loads
        uint4 raw[8];
        float wt[8];
        #pragma unroll
        for (int pp = 0; pp < 2; ++pp) {
            const int j = h * 12 + rep * 6 + g * 2 + pp;
            const int4   ix = *reinterpret_cast<const int4*>(&s_idx[qsel][j][0]);
            const float4 tw = *reinterpret_cast<const float4*>(&s_twt[qsel][j][0]);
            raw[pp * 4 + 0] = *reinterpret_cast<const uint4*>(vb + ix.x);
            raw[pp * 4 + 1] = *reinterpret_cast<const uint4*>(vb + ix.y);
            raw[pp * 4 + 2] = *reinterpret_cast<const uint4*>(vb + ix.z);
            raw[pp * 4 + 3] = *reinterpret_cast<const uint4*>(vb + ix.w);
            wt[pp * 4 + 0] = tw.x; wt[pp * 4 + 1] = tw.y;
            wt[pp * 4 + 2] = tw.z; wt[pp * 4 + 3] = tw.w;
        }
        #pragma unroll
        for (int k = 0; k < 8; ++k) {
            acc[0] += wt[k] * __uint_as_float(raw[k].x << 16);
            acc[1] += wt[k] * __uint_as_float(raw[k].x & 0xffff0000u);
            acc[2] += wt[k] * __uint_as_float(raw[k].y << 16);
            acc[3] += wt[k] * __uint_as_float(raw[k].y & 0xffff0000u);
            acc[4] += wt[k] * __uint_as_float(raw[k].z << 16);
            acc[5] += wt[k] * __uint_as_float(raw[k].z & 0xffff0000u);
            acc[6] += wt[k] * __uint_as_float(raw[k].w << 16);
            acc[7] += wt[k] * __uint_as_float(raw[k].w & 0xffff0000u);
        }
    }

    // combine the two tap-replicas (lanes differ in bit 2)
    #pragma unroll
    for (int c = 0; c < 8; ++c)
        acc[c] += __shfl_xor(acc[c], 4);

    if (rep == 0) {
        uint4 o;
        o.x = (u32)bf_of(acc[0]) | ((u32)bf_of(acc[1]) << 16);
        o.y = (u32)bf_of(acc[2]) | ((u32)bf_of(acc[3]) << 16);
        o.z = (u32)bf_of(acc[4]) | ((u32)bf_of(acc[5]) << 16);
        o.w = (u32)bf_of(acc[6]) | ((u32)bf_of(acc[7]) << 16);
        const size_t base = (size_t)bq * CDIM + h * HD + oct * 8;
        *reinterpret_cast<uint4*>(t_hi + base) = o;
    }
}

// ---------------------------------------------------------------------------
// Launch: 3 dispatches total.
// ---------------------------------------------------------------------------
extern "C" void kernel_launch(void* const* d_in, const int* in_sizes, int n_in,
                              void* d_out, int out_size, void* d_ws, size_t ws_size,
                              hipStream_t stream)
{
    const float* query = (const float*)d_in[0];   // (B,NQ,C)
    const float* refp  = (const float*)d_in[1];   // (B,NQ,2)
    const float* value = (const float*)d_in[2];   // (B,NV,C)
    const float* Wv    = (const float*)d_in[3];   // (C,C)
    const float* bv    = (const float*)d_in[4];
    const float* Woff  = (const float*)d_in[5];   // (192,C)
    const float* boff  = (const float*)d_in[6];
    const float* Wa    = (const float*)d_in[7];   // (96,C)
    const float* ba    = (const float*)d_in[8];
    const float* Wo    = (const float*)d_in[9];   // (C,C)
    const float* bo    = (const float*)d_in[10];
    float* out = (float*)d_out;

    // ---- workspace layout (all bf16) ----
    char* w = (char*)d_ws;
    const size_t SZ_T = (size_t)MROWS * CDIM * 2;     // 5.5 MB
    u16* v_bf16 = (u16*)(w);                          // head-major gather source
    u16* t_hi   = (u16*)(w + 1 * SZ_T);
    u16* ws_off = (u16*)(w + 2 * SZ_T);               // (MROWS,192) bf16
    u16* ws_a   = (u16*)(w + 2 * SZ_T + (size_t)MROWS * NOFF * 2);

    const dim3 blk(256);

    // 1) v-GEMM (bf16 head-major out) + qa-GEMM (bf16 off||a out), fp32 in
    gemm_vqa_kernel<<<dim3(VBLOCKS + (MROWS / GBM) * 5), blk, 0, stream>>>(
        value, Wv, bv, v_bf16,
        query, Woff, Wa, boff, ba, ws_off, ws_a);

    // 2) sampling core -> t_hi (bf16)
    msda_core_kernel<<<dim3(MROWS / 4), blk, 0, stream>>>(
        ws_off, ws_a, refp, v_bf16, t_hi);

    // 3) out = t @ Wo^T + bo (fp32 out)
    gemm_out_kernel<<<dim3((MROWS / GBM) * 4), blk, 0, stream>>>(
        t_hi, Wo, bo, out);
}